// Round 2
// baseline (711.646 us; speedup 1.0000x reference)
//
#include <hip/hip_runtime.h>
#include <math.h>

#define N_TOK 1024
#define D_MODEL 128
#define NHEAD 4
#define HD 32
#define FF_DIM 2048
#define H_PAIR 128

// ---------------- embedding lookup ----------------
__global__ void embed_kernel(const int* __restrict__ ids, const float* __restrict__ emb,
                             float* __restrict__ x) {
    int idx = blockIdx.x * 256 + threadIdx.x;      // N_TOK*D_MODEL total
    int i = idx >> 7, d = idx & 127;
    x[idx] = emb[ids[i] * D_MODEL + d];
}

// ---------------- generic fp32 GEMM: C = X(M,K) @ W(N,K)^T (+bias)(+res)(relu?) ----
// 32x32 tile, 16x16 threads, 2x2 microtile, TK=16. All dims multiples of 32/16.
__global__ void gemm_xwt(const float* __restrict__ X, const float* __restrict__ W, int ldw,
                         const float* __restrict__ bias, const float* __restrict__ res,
                         float* __restrict__ C, int M, int Nc, int K, int act) {
    __shared__ float Xs[32][17];
    __shared__ float Ws[32][17];
    const int tx = threadIdx.x, ty = threadIdx.y;
    const int t = ty * 16 + tx;
    const int rowBase = blockIdx.y * 32;
    const int colBase = blockIdx.x * 32;
    float acc00 = 0.f, acc01 = 0.f, acc10 = 0.f, acc11 = 0.f;
    for (int k0 = 0; k0 < K; k0 += 16) {
#pragma unroll
        for (int u = 0; u < 2; ++u) {
            int idx = t + u * 256;
            int r = idx >> 4, k = idx & 15;
            Xs[r][k] = X[(rowBase + r) * K + k0 + k];
            Ws[r][k] = W[(colBase + r) * ldw + k0 + k];
        }
        __syncthreads();
#pragma unroll
        for (int k = 0; k < 16; ++k) {
            float x0 = Xs[ty][k], x1 = Xs[ty + 16][k];
            float w0 = Ws[tx][k], w1 = Ws[tx + 16][k];
            acc00 += x0 * w0; acc01 += x0 * w1;
            acc10 += x1 * w0; acc11 += x1 * w1;
        }
        __syncthreads();
    }
#pragma unroll
    for (int a = 0; a < 2; ++a) {
#pragma unroll
        for (int b = 0; b < 2; ++b) {
            float v = (a == 0) ? (b == 0 ? acc00 : acc01) : (b == 0 ? acc10 : acc11);
            int m = rowBase + ty + a * 16;
            int n = colBase + tx + b * 16;
            if (bias) v += bias[n];
            if (res)  v += res[m * Nc + n];
            if (act == 1) v = fmaxf(v, 0.f);
            C[m * Nc + n] = v;
        }
    }
}

// ---------------- attention: one block per (query i, head h) ----------------
__global__ void attn_kernel(const float* __restrict__ qkv, float* __restrict__ attn_o) {
    const int i = blockIdx.x;
    const int h = blockIdx.y;
    const int t = threadIdx.x;                 // 256 threads
    __shared__ float qs[HD];
    __shared__ float p[N_TOK];
    __shared__ float red[8][HD];
    __shared__ float rtmp[4];
    if (t < HD) qs[t] = qkv[i * 384 + h * HD + t];
    __syncthreads();

    float sloc[4];
    float lmax = -1e30f;
#pragma unroll
    for (int c = 0; c < 4; ++c) {
        int j = t + c * 256;
        const float* kr = qkv + j * 384 + D_MODEL + h * HD;
        float s = 0.f;
#pragma unroll
        for (int d = 0; d < HD; ++d) s += qs[d] * kr[d];
        s *= 0.17677669529663687f;   // 1/sqrt(32)
        sloc[c] = s;
        lmax = fmaxf(lmax, s);
    }
    for (int o = 32; o; o >>= 1) lmax = fmaxf(lmax, __shfl_down(lmax, o));
    if ((t & 63) == 0) rtmp[t >> 6] = lmax;
    __syncthreads();
    float gmax = fmaxf(fmaxf(rtmp[0], rtmp[1]), fmaxf(rtmp[2], rtmp[3]));

    float lsum = 0.f;
#pragma unroll
    for (int c = 0; c < 4; ++c) {
        float e = __expf(sloc[c] - gmax);
        p[t + c * 256] = e;
        lsum += e;
    }
    for (int o = 32; o; o >>= 1) lsum += __shfl_down(lsum, o);
    __syncthreads();                  // everyone done reading rtmp (max) + writing p
    if ((t & 63) == 0) rtmp[t >> 6] = lsum;
    __syncthreads();
    float inv = 1.0f / (rtmp[0] + rtmp[1] + rtmp[2] + rtmp[3]);

    // PV: 8 groups x 32 dims
    const int d = t & 31;
    const int g = t >> 5;
    float partial = 0.f;
    for (int j = g; j < N_TOK; j += 8)
        partial += p[j] * qkv[j * 384 + 2 * D_MODEL + h * HD + d];
    red[g][d] = partial;
    __syncthreads();
    if (t < HD) {
        float acc = 0.f;
#pragma unroll
        for (int g2 = 0; g2 < 8; ++g2) acc += red[g2][t];
        attn_o[i * D_MODEL + h * HD + t] = acc * inv;
    }
}

// ---------------- LayerNorm: one wave per row of 128 ----------------
__global__ void ln_kernel(const float* __restrict__ in, const float* __restrict__ s,
                          const float* __restrict__ b, float* __restrict__ outp) {
    const int i = blockIdx.x;
    const int t = threadIdx.x;  // 64
    float v0 = in[i * 128 + t];
    float v1 = in[i * 128 + 64 + t];
    float sum = v0 + v1;
    for (int o = 32; o; o >>= 1) sum += __shfl_down(sum, o);
    sum = __shfl(sum, 0);
    float mean = sum * (1.0f / 128.0f);
    float d0 = v0 - mean, d1 = v1 - mean;
    float vs = d0 * d0 + d1 * d1;
    for (int o = 32; o; o >>= 1) vs += __shfl_down(vs, o);
    vs = __shfl(vs, 0);
    float inv = rsqrtf(vs * (1.0f / 128.0f) + 1e-5f);
    outp[i * 128 + t]      = d0 * inv * s[t]      + b[t];
    outp[i * 128 + 64 + t] = d1 * inv * s[64 + t] + b[64 + t];
}

// ---------------- pair MLP: out[i][j] = sum_k relu(a_ik + b_jk + b1_k) * w2_k + b2 ----
// 32x32 outputs per block, 16x16 threads, 2x2 microtile.
__global__ void pair_kernel(const float* __restrict__ A, const float* __restrict__ B,
                            const float* __restrict__ b1, const float* __restrict__ w2,
                            const float* __restrict__ b2p, float* __restrict__ outp) {
    __shared__ float As[32][H_PAIR + 1];  // a + b1 folded in
    __shared__ float Bs[32][H_PAIR + 1];
    __shared__ float w2s[H_PAIR];
    const int tx = threadIdx.x, ty = threadIdx.y;
    const int t = ty * 16 + tx;
    const int i0 = blockIdx.y * 32, j0 = blockIdx.x * 32;
    for (int u = t; u < 32 * H_PAIR; u += 256) {
        int r = u >> 7, k = u & 127;
        As[r][k] = A[(i0 + r) * H_PAIR + k] + b1[k];
        Bs[r][k] = B[(j0 + r) * H_PAIR + k];
    }
    if (t < H_PAIR) w2s[t] = w2[t];
    __syncthreads();
    float a00 = 0.f, a01 = 0.f, a10 = 0.f, a11 = 0.f;
#pragma unroll 8
    for (int k = 0; k < H_PAIR; ++k) {
        float x0 = As[ty][k],      x1 = As[ty + 16][k];
        float y0 = Bs[tx][k],      y1 = Bs[tx + 16][k];
        float w = w2s[k];
        a00 += fmaxf(x0 + y0, 0.f) * w;
        a01 += fmaxf(x0 + y1, 0.f) * w;
        a10 += fmaxf(x1 + y0, 0.f) * w;
        a11 += fmaxf(x1 + y1, 0.f) * w;
    }
    float bb = b2p[0];
    outp[(i0 + ty) * N_TOK + (j0 + tx)]           = a00 + bb;
    outp[(i0 + ty) * N_TOK + (j0 + tx + 16)]      = a01 + bb;
    outp[(i0 + ty + 16) * N_TOK + (j0 + tx)]      = a10 + bb;
    outp[(i0 + ty + 16) * N_TOK + (j0 + tx + 16)] = a11 + bb;
}

extern "C" void kernel_launch(void* const* d_in, const int* in_sizes, int n_in,
                              void* d_out, int out_size, void* d_ws, size_t ws_size,
                              hipStream_t stream) {
    const int*   ids   = (const int*)d_in[0];
    const float* emb   = (const float*)d_in[1];
    const float* qkv_w = (const float*)d_in[2];
    const float* qkv_b = (const float*)d_in[3];
    const float* ow    = (const float*)d_in[4];
    const float* ob    = (const float*)d_in[5];
    const float* ln1_s = (const float*)d_in[6];
    const float* ln1_b = (const float*)d_in[7];
    const float* ln2_s = (const float*)d_in[8];
    const float* ln2_b = (const float*)d_in[9];
    const float* ff1_w = (const float*)d_in[10];
    const float* ff1_b = (const float*)d_in[11];
    const float* ff2_w = (const float*)d_in[12];
    const float* ff2_b = (const float*)d_in[13];
    const float* w1    = (const float*)d_in[14];
    const float* b1    = (const float*)d_in[15];
    const float* w2    = (const float*)d_in[16];
    const float* b2    = (const float*)d_in[17];
    float* out = (float*)d_out;

    float* ws    = (float*)d_ws;
    float* x      = ws;                    // 1024*128
    float* qkv    = x + 1024 * 128;        // 1024*384
    float* attn_o = qkv + 1024 * 384;      // 1024*128
    float* tmp    = attn_o + 1024 * 128;   // 1024*128
    float* ff     = tmp + 1024 * 128;      // 1024*2048
    float* pa     = ff + 1024 * 2048;      // 1024*128
    float* pb     = pa + 1024 * 128;       // 1024*128

    dim3 thr(16, 16);

    embed_kernel<<<512, 256, 0, stream>>>(ids, emb, x);

    for (int l = 0; l < 2; ++l) {
        const float* qw  = qkv_w + l * 384 * 128;
        const float* qb  = qkv_b + l * 384;
        const float* owl = ow + l * 128 * 128;
        const float* obl = ob + l * 128;
        const float* f1w = ff1_w + l * 2048 * 128;
        const float* f1b = ff1_b + l * 2048;
        const float* f2w = ff2_w + l * 128 * 2048;
        const float* f2b = ff2_b + l * 128;

        // qkv = x @ qkv_w^T + qkv_b      (1024,384) K=128
        gemm_xwt<<<dim3(384 / 32, 1024 / 32), thr, 0, stream>>>(
            x, qw, 128, qb, nullptr, qkv, 1024, 384, 128, 0);
        // attention
        attn_kernel<<<dim3(1024, NHEAD), 256, 0, stream>>>(qkv, attn_o);
        // tmp = attn_o @ ow^T + ob + x   (residual)
        gemm_xwt<<<dim3(128 / 32, 1024 / 32), thr, 0, stream>>>(
            attn_o, owl, 128, obl, x, tmp, 1024, 128, 128, 0);
        // x = LN1(tmp)
        ln_kernel<<<1024, 64, 0, stream>>>(tmp, ln1_s + l * 128, ln1_b + l * 128, x);
        // ff = relu(x @ ff1^T + b)       (1024,2048) K=128
        gemm_xwt<<<dim3(2048 / 32, 1024 / 32), thr, 0, stream>>>(
            x, f1w, 128, f1b, nullptr, ff, 1024, 2048, 128, 1);
        // tmp = ff @ ff2^T + b + x       (1024,128) K=2048
        gemm_xwt<<<dim3(128 / 32, 1024 / 32), thr, 0, stream>>>(
            ff, f2w, 2048, f2b, x, tmp, 1024, 128, 2048, 0);
        // x = LN2(tmp)
        ln_kernel<<<1024, 64, 0, stream>>>(tmp, ln2_s + l * 128, ln2_b + l * 128, x);
    }

    // pair head: a = x @ w1[:, :128]^T ; b = x @ w1[:, 128:]^T   (ldw = 256)
    gemm_xwt<<<dim3(128 / 32, 1024 / 32), thr, 0, stream>>>(
        x, w1, 256, nullptr, nullptr, pa, 1024, 128, 128, 0);
    gemm_xwt<<<dim3(128 / 32, 1024 / 32), thr, 0, stream>>>(
        x, w1 + 128, 256, nullptr, nullptr, pb, 1024, 128, 128, 0);
    // out[i][j] = sum_k relu(pa_ik + pb_jk + b1_k) * w2_k + b2
    pair_kernel<<<dim3(1024 / 32, 1024 / 32), thr, 0, stream>>>(
        pa, pb, b1, w2, b2, out);
}

// Round 5
// 299.689 us; speedup vs baseline: 2.3746x; 2.3746x over previous
//
#include <hip/hip_runtime.h>
#include <math.h>

#define N_TOK 1024
#define D_MODEL 128
#define NHEAD 4
#define HD 32
#define FF_DIM 2048
#define H_PAIR 128
#define QK_SCALE 0.17677669529663687f  // 1/sqrt(32)

// ---------------- embedding lookup (float4) ----------------
__global__ void embed_kernel(const int* __restrict__ ids, const float* __restrict__ emb,
                             float* __restrict__ x) {
    int u = blockIdx.x * 256 + threadIdx.x;        // 1024*32 float4s
    int i = u >> 5, d4 = (u & 31) * 4;
    float4 v = *(const float4*)&emb[(size_t)ids[i] * D_MODEL + d4];
    *(float4*)&x[i * D_MODEL + d4] = v;
}

// ---------------- GEMM v2: C = X(M,K) @ W(N,K)^T, 64x64 tile, 4x4 micro ----------------
// If part != nullptr: split-K, write raw partial to part[z*M*N + ...] (no bias/res/act).
__global__ __launch_bounds__(256) void gemm64(const float* __restrict__ X,
                                              const float* __restrict__ W, int ldw,
                                              const float* __restrict__ bias,
                                              const float* __restrict__ res,
                                              float* __restrict__ C, int M, int Nc, int K,
                                              int act, int kChunk, float* __restrict__ part) {
    __shared__ float Xs[16][68];   // [k][m] transposed; stride 68 -> 2-way max conflicts
    __shared__ float Ws[16][68];   // [k][n]
    const int t = threadIdx.x;
    const int tx = t & 15, ty = t >> 4;
    const int m0 = blockIdx.y * 64, n0 = blockIdx.x * 64;
    const int kbase = blockIdx.z * kChunk;

    const int sr = t >> 2;              // staging row 0..63
    const int skq = (t & 3) * 4;        // staging k quad
    const float* Xp = X + (size_t)(m0 + sr) * K + kbase + skq;
    const float* Wp = W + (size_t)(n0 + sr) * ldw + kbase + skq;

    float acc[4][4] = {};
    float4 xa = *(const float4*)Xp;
    float4 wa = *(const float4*)Wp;

    for (int k0 = 0; k0 < kChunk; k0 += 16) {
        __syncthreads();   // previous compute done
        Xs[skq + 0][sr] = xa.x; Xs[skq + 1][sr] = xa.y;
        Xs[skq + 2][sr] = xa.z; Xs[skq + 3][sr] = xa.w;
        Ws[skq + 0][sr] = wa.x; Ws[skq + 1][sr] = wa.y;
        Ws[skq + 2][sr] = wa.z; Ws[skq + 3][sr] = wa.w;
        __syncthreads();
        if (k0 + 16 < kChunk) {        // prefetch next k-slab during compute
            xa = *(const float4*)(Xp + k0 + 16);
            wa = *(const float4*)(Wp + k0 + 16);
        }
#pragma unroll
        for (int k = 0; k < 16; ++k) {
            float4 a = *(const float4*)&Xs[k][ty * 4];
            float4 b = *(const float4*)&Ws[k][tx * 4];
            acc[0][0] += a.x * b.x; acc[0][1] += a.x * b.y; acc[0][2] += a.x * b.z; acc[0][3] += a.x * b.w;
            acc[1][0] += a.y * b.x; acc[1][1] += a.y * b.y; acc[1][2] += a.y * b.z; acc[1][3] += a.y * b.w;
            acc[2][0] += a.z * b.x; acc[2][1] += a.z * b.y; acc[2][2] += a.z * b.z; acc[2][3] += a.z * b.w;
            acc[3][0] += a.w * b.x; acc[3][1] += a.w * b.y; acc[3][2] += a.w * b.z; acc[3][3] += a.w * b.w;
        }
    }

    if (part) {
        float* P = part + (size_t)blockIdx.z * M * Nc;
#pragma unroll
        for (int i = 0; i < 4; ++i) {
            int m = m0 + ty * 4 + i;
            *(float4*)&P[(size_t)m * Nc + n0 + tx * 4] =
                make_float4(acc[i][0], acc[i][1], acc[i][2], acc[i][3]);
        }
    } else {
        float4 bv = make_float4(0.f, 0.f, 0.f, 0.f);
        if (bias) bv = *(const float4*)&bias[n0 + tx * 4];
#pragma unroll
        for (int i = 0; i < 4; ++i) {
            int m = m0 + ty * 4 + i;
            float4 v = make_float4(acc[i][0] + bv.x, acc[i][1] + bv.y,
                                   acc[i][2] + bv.z, acc[i][3] + bv.w);
            if (res) {
                float4 rv = *(const float4*)&res[(size_t)m * Nc + n0 + tx * 4];
                v.x += rv.x; v.y += rv.y; v.z += rv.z; v.w += rv.w;
            }
            if (act) {
                v.x = fmaxf(v.x, 0.f); v.y = fmaxf(v.y, 0.f);
                v.z = fmaxf(v.z, 0.f); v.w = fmaxf(v.w, 0.f);
            }
            *(float4*)&C[(size_t)m * Nc + n0 + tx * 4] = v;
        }
    }
}

// ---------------- flash attention: block = (16 queries, 1 head), 256 threads ----------------
// Scores are tiny (|s| << 1): exp without max-subtraction == exact softmax after normalize.
__global__ __launch_bounds__(256) void attn_flash(const float* __restrict__ qkv,
                                                  float* __restrict__ attn_o) {
    const int h = blockIdx.y;
    const int q0 = blockIdx.x * 16;
    const int t = threadIdx.x;
    const int qi = t & 15;          // query row within tile
    const int g = t >> 4;           // j-group 0..15 (owns 4 j's per 64-tile)
    __shared__ float Kt[64][36];
    __shared__ float Vt[64][36];
    __shared__ float opart[16][16][36];  // [g][qi][d]
    __shared__ float rsum[16][17];       // [qi][g]

    float qreg[32];
    const float* Qp = qkv + (size_t)(q0 + qi) * 384 + h * HD;
#pragma unroll
    for (int d4 = 0; d4 < 8; ++d4) {
        float4 v = *(const float4*)(Qp + d4 * 4);
        qreg[d4 * 4 + 0] = v.x * QK_SCALE; qreg[d4 * 4 + 1] = v.y * QK_SCALE;
        qreg[d4 * 4 + 2] = v.z * QK_SCALE; qreg[d4 * 4 + 3] = v.w * QK_SCALE;
    }
    float opar[32] = {};
    float psum = 0.f;

    for (int j0 = 0; j0 < N_TOK; j0 += 64) {
        __syncthreads();   // previous tile's reads done
#pragma unroll
        for (int u = 0; u < 2; ++u) {
            int uu = t + u * 256;
            int r = uu >> 3, dq = (uu & 7) * 4;
            const float* src = qkv + (size_t)(j0 + r) * 384 + D_MODEL + h * HD + dq;
            float4 kv = *(const float4*)src;
            float4 vv = *(const float4*)(src + D_MODEL);   // V is +128 after K
            *(float4*)&Kt[r][dq] = kv;
            *(float4*)&Vt[r][dq] = vv;
        }
        __syncthreads();
#pragma unroll
        for (int jj = 0; jj < 4; ++jj) {
            const int jl = g * 4 + jj;
            float s = 0.f;
#pragma unroll
            for (int d4 = 0; d4 < 8; ++d4) {
                float4 kv = *(const float4*)&Kt[jl][d4 * 4];
                s += qreg[d4 * 4 + 0] * kv.x + qreg[d4 * 4 + 1] * kv.y
                   + qreg[d4 * 4 + 2] * kv.z + qreg[d4 * 4 + 3] * kv.w;
            }
            float p = __expf(s);
            psum += p;
#pragma unroll
            for (int d4 = 0; d4 < 8; ++d4) {
                float4 vv = *(const float4*)&Vt[jl][d4 * 4];
                opar[d4 * 4 + 0] += p * vv.x; opar[d4 * 4 + 1] += p * vv.y;
                opar[d4 * 4 + 2] += p * vv.z; opar[d4 * 4 + 3] += p * vv.w;
            }
        }
    }

#pragma unroll
    for (int d4 = 0; d4 < 8; ++d4)
        *(float4*)&opart[g][qi][d4 * 4] = make_float4(opar[d4 * 4 + 0], opar[d4 * 4 + 1],
                                                      opar[d4 * 4 + 2], opar[d4 * 4 + 3]);
    rsum[qi][g] = psum;
    __syncthreads();

    {
        const int qi2 = t & 15;
        const int d0 = (t >> 4) * 2;
        float ssum = 0.f;
#pragma unroll
        for (int gg = 0; gg < 16; ++gg) ssum += rsum[qi2][gg];
        float inv = 1.0f / ssum;
        float o0 = 0.f, o1 = 0.f;
#pragma unroll
        for (int gg = 0; gg < 16; ++gg) {
            o0 += opart[gg][qi2][d0];
            o1 += opart[gg][qi2][d0 + 1];
        }
        float* dst = attn_o + (size_t)(q0 + qi2) * D_MODEL + h * HD + d0;
        dst[0] = o0 * inv;
        dst[1] = o1 * inv;
    }
}

// ---------------- LayerNorm (+ optional nz-partial reduce + bias + residual) ----------------
__global__ void ln_red(const float* __restrict__ in, int nz, int zstride,
                       const float* __restrict__ bias, const float* __restrict__ res,
                       const float* __restrict__ s, const float* __restrict__ b,
                       float* __restrict__ outp) {
    const int i = blockIdx.x;
    const int t = threadIdx.x;  // 64
    float v0 = 0.f, v1 = 0.f;
    for (int z = 0; z < nz; ++z) {
        v0 += in[(size_t)z * zstride + i * 128 + t];
        v1 += in[(size_t)z * zstride + i * 128 + 64 + t];
    }
    if (bias) { v0 += bias[t]; v1 += bias[64 + t]; }
    if (res)  { v0 += res[i * 128 + t]; v1 += res[i * 128 + 64 + t]; }
    float sum = v0 + v1;
    for (int o = 32; o; o >>= 1) sum += __shfl_down(sum, o);
    sum = __shfl(sum, 0);
    float mean = sum * (1.0f / 128.0f);
    float d0 = v0 - mean, d1 = v1 - mean;
    float vs = d0 * d0 + d1 * d1;
    for (int o = 32; o; o >>= 1) vs += __shfl_down(vs, o);
    vs = __shfl(vs, 0);
    float inv = rsqrtf(vs * (1.0f / 128.0f) + 1e-5f);
    outp[i * 128 + t]      = d0 * inv * s[t]      + b[t];
    outp[i * 128 + 64 + t] = d1 * inv * s[64 + t] + b[64 + t];
}

// ---------------- pair MLP (float4 inner) ----------------
__global__ __launch_bounds__(256) void pair_kernel(const float* __restrict__ A,
                                                   const float* __restrict__ B,
                                                   const float* __restrict__ b1,
                                                   const float* __restrict__ w2,
                                                   const float* __restrict__ b2p,
                                                   float* __restrict__ outp) {
    __shared__ float As[32][132];
    __shared__ float Bs[32][132];
    __shared__ float w2s[128];
    const int t = threadIdx.x;
    const int tx = t & 15, ty = t >> 4;
    const int i0 = blockIdx.y * 32, j0 = blockIdx.x * 32;
    for (int u = t; u < 1024; u += 256) {         // 32 rows x 32 float4
        int r = u >> 5, kq = (u & 31) * 4;
        float4 av = *(const float4*)&A[(size_t)(i0 + r) * 128 + kq];
        float4 bb1 = *(const float4*)&b1[kq];
        av.x += bb1.x; av.y += bb1.y; av.z += bb1.z; av.w += bb1.w;
        *(float4*)&As[r][kq] = av;
        *(float4*)&Bs[r][kq] = *(const float4*)&B[(size_t)(j0 + r) * 128 + kq];
    }
    if (t < 32) *(float4*)&w2s[t * 4] = *(const float4*)&w2[t * 4];
    __syncthreads();
    float a00 = 0.f, a01 = 0.f, a10 = 0.f, a11 = 0.f;
#pragma unroll 4
    for (int k4 = 0; k4 < 32; ++k4) {
        float4 x0 = *(const float4*)&As[ty][k4 * 4];
        float4 x1 = *(const float4*)&As[ty + 16][k4 * 4];
        float4 y0 = *(const float4*)&Bs[tx][k4 * 4];
        float4 y1 = *(const float4*)&Bs[tx + 16][k4 * 4];
        float4 w = *(const float4*)&w2s[k4 * 4];
        a00 += fmaxf(x0.x + y0.x, 0.f) * w.x + fmaxf(x0.y + y0.y, 0.f) * w.y
             + fmaxf(x0.z + y0.z, 0.f) * w.z + fmaxf(x0.w + y0.w, 0.f) * w.w;
        a01 += fmaxf(x0.x + y1.x, 0.f) * w.x + fmaxf(x0.y + y1.y, 0.f) * w.y
             + fmaxf(x0.z + y1.z, 0.f) * w.z + fmaxf(x0.w + y1.w, 0.f) * w.w;
        a10 += fmaxf(x1.x + y0.x, 0.f) * w.x + fmaxf(x1.y + y0.y, 0.f) * w.y
             + fmaxf(x1.z + y0.z, 0.f) * w.z + fmaxf(x1.w + y0.w, 0.f) * w.w;
        a11 += fmaxf(x1.x + y1.x, 0.f) * w.x + fmaxf(x1.y + y1.y, 0.f) * w.y
             + fmaxf(x1.z + y1.z, 0.f) * w.z + fmaxf(x1.w + y1.w, 0.f) * w.w;
    }
    float bb = b2p[0];
    outp[(size_t)(i0 + ty) * N_TOK + j0 + tx]            = a00 + bb;
    outp[(size_t)(i0 + ty) * N_TOK + j0 + tx + 16]       = a01 + bb;
    outp[(size_t)(i0 + ty + 16) * N_TOK + j0 + tx]       = a10 + bb;
    outp[(size_t)(i0 + ty + 16) * N_TOK + j0 + tx + 16]  = a11 + bb;
}

extern "C" void kernel_launch(void* const* d_in, const int* in_sizes, int n_in,
                              void* d_out, int out_size, void* d_ws, size_t ws_size,
                              hipStream_t stream) {
    const int*   ids   = (const int*)d_in[0];
    const float* emb   = (const float*)d_in[1];
    const float* qkv_w = (const float*)d_in[2];
    const float* qkv_b = (const float*)d_in[3];
    const float* ow    = (const float*)d_in[4];
    const float* ob    = (const float*)d_in[5];
    const float* ln1_s = (const float*)d_in[6];
    const float* ln1_b = (const float*)d_in[7];
    const float* ln2_s = (const float*)d_in[8];
    const float* ln2_b = (const float*)d_in[9];
    const float* ff1_w = (const float*)d_in[10];
    const float* ff1_b = (const float*)d_in[11];
    const float* ff2_w = (const float*)d_in[12];
    const float* ff2_b = (const float*)d_in[13];
    const float* w1    = (const float*)d_in[14];
    const float* b1    = (const float*)d_in[15];
    const float* w2    = (const float*)d_in[16];
    const float* b2    = (const float*)d_in[17];
    float* out = (float*)d_out;

    float* ws     = (float*)d_ws;
    float* x      = ws;                      // 1024*128
    float* qkvb   = x + 1024 * 128;          // 1024*384
    float* attn_o = qkvb + 1024 * 384;       // 1024*128
    float* tmp    = attn_o + 1024 * 128;     // 1024*128
    float* ff     = tmp + 1024 * 128;        // 1024*2048
    float* part   = ff + 1024 * 2048;        // 8*1024*128 (split-K partials)
    float* pa     = part;                    // reuse: part dead before pair head
    float* pb     = pa + 1024 * 128;

    embed_kernel<<<128, 256, 0, stream>>>(ids, emb, x);

    for (int l = 0; l < 2; ++l) {
        const float* qw  = qkv_w + l * 384 * 128;
        const float* qb  = qkv_b + l * 384;
        const float* owl = ow + l * 128 * 128;
        const float* obl = ob + l * 128;
        const float* f1w = ff1_w + l * 2048 * 128;
        const float* f1b = ff1_b + l * 2048;
        const float* f2w = ff2_w + l * 128 * 2048;
        const float* f2b = ff2_b + l * 128;

        // qkv = x @ qkv_w^T + b
        gemm64<<<dim3(6, 16, 1), 256, 0, stream>>>(x, qw, 128, qb, nullptr, qkvb,
                                                   1024, 384, 128, 0, 128, nullptr);
        // attention
        attn_flash<<<dim3(64, NHEAD), 256, 0, stream>>>(qkvb, attn_o);
        // tmp = attn_o @ ow^T + ob + x
        gemm64<<<dim3(2, 16, 1), 256, 0, stream>>>(attn_o, owl, 128, obl, x, tmp,
                                                   1024, 128, 128, 0, 128, nullptr);
        // x = LN1(tmp)
        ln_red<<<1024, 64, 0, stream>>>(tmp, 1, 0, nullptr, nullptr,
                                        ln1_s + l * 128, ln1_b + l * 128, x);
        // ff = relu(x @ ff1^T + b)
        gemm64<<<dim3(32, 16, 1), 256, 0, stream>>>(x, f1w, 128, f1b, nullptr, ff,
                                                    1024, 2048, 128, 1, 128, nullptr);
        // part[z] = ff @ ff2^T (split-K over 2048, 8 chunks)
        gemm64<<<dim3(2, 16, 8), 256, 0, stream>>>(ff, f2w, 2048, nullptr, nullptr, nullptr,
                                                   1024, 128, 2048, 0, 256, part);
        // x = LN2(sum_z part + f2b + x)
        ln_red<<<1024, 64, 0, stream>>>(part, 8, 1024 * 128, f2b, x,
                                        ln2_s + l * 128, ln2_b + l * 128, x);
    }

    // pair head
    gemm64<<<dim3(2, 16, 1), 256, 0, stream>>>(x, w1, 256, nullptr, nullptr, pa,
                                               1024, 128, 128, 0, 128, nullptr);
    gemm64<<<dim3(2, 16, 1), 256, 0, stream>>>(x, w1 + 128, 256, nullptr, nullptr, pb,
                                               1024, 128, 128, 0, 128, nullptr);
    pair_kernel<<<dim3(32, 32), 256, 0, stream>>>(pa, pb, b1, w2, b2, out);
}

// Round 6
// 283.616 us; speedup vs baseline: 2.5092x; 1.0567x over previous
//
#include <hip/hip_runtime.h>
#include <math.h>

#define N_TOK 1024
#define D_MODEL 128
#define NHEAD 4
#define HD 32
#define FF_DIM 2048
#define H_PAIR 128
#define QK_SCALE 0.17677669529663687f  // 1/sqrt(32)

typedef __attribute__((ext_vector_type(8))) short bf16x8;
typedef __attribute__((ext_vector_type(4))) float f32x4;

__device__ __forceinline__ unsigned short f2bf(float f) {
    unsigned u = __float_as_uint(f);
    u = u + 0x7FFFu + ((u >> 16) & 1u);   // RNE
    return (unsigned short)(u >> 16);
}

// ---------------- weight conversion: 4 flat fp32 regions -> bf16 ----------------
__global__ void cvt4_kernel(const float* __restrict__ s0, int n0, const float* __restrict__ s1, int n1,
                            const float* __restrict__ s2, int n2, const float* __restrict__ s3, int n3,
                            unsigned short* __restrict__ d0, unsigned short* __restrict__ d1,
                            unsigned short* __restrict__ d2, unsigned short* __restrict__ d3) {
    int i = blockIdx.x * 256 + threadIdx.x;
    if (i < n0) { d0[i] = f2bf(s0[i]); return; } i -= n0;
    if (i < n1) { d1[i] = f2bf(s1[i]); return; } i -= n1;
    if (i < n2) { d2[i] = f2bf(s2[i]); return; } i -= n2;
    if (i < n3) { d3[i] = f2bf(s3[i]); }
}

// ---------------- w1 (H, 2D) -> w1L (H,D) bf16, w1R (H,D) bf16 ----------------
__global__ void w1split_kernel(const float* __restrict__ w1, unsigned short* __restrict__ w1L,
                               unsigned short* __restrict__ w1R) {
    int h = blockIdx.x, t = threadIdx.x;   // 128 blocks, 256 threads
    float v = w1[h * 256 + t];
    if (t < 128) w1L[h * 128 + t] = f2bf(v);
    else         w1R[h * 128 + (t - 128)] = f2bf(v);
}

// ---------------- embedding: fp32 x + bf16 xb ----------------
__global__ void embed_kernel(const int* __restrict__ ids, const float* __restrict__ emb,
                             float* __restrict__ x, unsigned short* __restrict__ xb) {
    int u = blockIdx.x * 256 + threadIdx.x;        // 1024*32 float4s
    int i = u >> 5, d4 = (u & 31) * 4;
    float4 v = *(const float4*)&emb[(size_t)ids[i] * D_MODEL + d4];
    *(float4*)&x[i * D_MODEL + d4] = v;
    ushort4 bv;
    bv.x = f2bf(v.x); bv.y = f2bf(v.y); bv.z = f2bf(v.z); bv.w = f2bf(v.w);
    *(ushort4*)&xb[i * D_MODEL + d4] = bv;
}

// ---------------- bf16 MFMA GEMM: C = Xb(M,K) @ Wb(N,K)^T ----------------
// 64x64 tile, 4 waves, each wave = 16 rows x 64 cols, K-step 32.
// Modes: part!=null -> split-K raw partial (kb = z*kChunk).
//        Wb2!=null  -> dual-weight (z selects Wb/Wb2, output offset z*M*Nc).
__global__ __launch_bounds__(256) void gemm_bf(const unsigned short* __restrict__ Xb,
                                               const unsigned short* __restrict__ Wb,
                                               const unsigned short* __restrict__ Wb2,
                                               const float* __restrict__ bias,
                                               const float* __restrict__ res,
                                               float* __restrict__ Cf,
                                               unsigned short* __restrict__ Cb,
                                               float* __restrict__ part,
                                               int M, int Nc, int K, int kChunk, int act) {
    const int lane = threadIdx.x & 63;
    const int w = threadIdx.x >> 6;
    const int m0 = blockIdx.y * 64 + w * 16;
    const int n0 = blockIdx.x * 64;
    const int kb = part ? blockIdx.z * kChunk : 0;
    const int r16 = lane & 15, kh = lane >> 4;

    const unsigned short* Wsel = (Wb2 && blockIdx.z == 1) ? Wb2 : Wb;

    f32x4 acc[4] = {{0.f,0.f,0.f,0.f},{0.f,0.f,0.f,0.f},{0.f,0.f,0.f,0.f},{0.f,0.f,0.f,0.f}};
    const unsigned short* Ap = Xb + (size_t)(m0 + r16) * K + kb + kh * 8;
    const unsigned short* Bp = Wsel + (size_t)(n0 + r16) * K + kb + kh * 8;

    for (int k0 = 0; k0 < kChunk; k0 += 32) {
        bf16x8 a = *(const bf16x8*)(Ap + k0);
#pragma unroll
        for (int nt = 0; nt < 4; ++nt) {
            bf16x8 b = *(const bf16x8*)(Bp + (size_t)nt * 16 * K + k0);
            acc[nt] = __builtin_amdgcn_mfma_f32_16x16x32_bf16(a, b, acc[nt], 0, 0, 0);
        }
    }

    if (part) {
        float* P = part + (size_t)blockIdx.z * M * Nc;
#pragma unroll
        for (int nt = 0; nt < 4; ++nt) {
            int col = n0 + nt * 16 + r16;
#pragma unroll
            for (int r = 0; r < 4; ++r) {
                int row = m0 + kh * 4 + r;
                P[(size_t)row * Nc + col] = acc[nt][r];
            }
        }
    } else {
        size_t zoff = (size_t)blockIdx.z * M * Nc;   // 0 unless dual-weight mode
#pragma unroll
        for (int nt = 0; nt < 4; ++nt) {
            int col = n0 + nt * 16 + r16;
            float bv = bias ? bias[col] : 0.f;
#pragma unroll
            for (int r = 0; r < 4; ++r) {
                int row = m0 + kh * 4 + r;
                float v = acc[nt][r] + bv;
                if (res) v += res[(size_t)row * Nc + col];
                if (act) v = fmaxf(v, 0.f);
                if (Cf) Cf[zoff + (size_t)row * Nc + col] = v;
                if (Cb) Cb[zoff + (size_t)row * Nc + col] = f2bf(v);
            }
        }
    }
}

// ---------------- flash attention (fp32), writes bf16 output ----------------
__global__ __launch_bounds__(256) void attn_flash(const float* __restrict__ qkv,
                                                  unsigned short* __restrict__ attn_ob) {
    const int h = blockIdx.y;
    const int q0 = blockIdx.x * 16;
    const int t = threadIdx.x;
    const int qi = t & 15;
    const int g = t >> 4;
    __shared__ float Kt[64][36];
    __shared__ float Vt[64][36];
    __shared__ float opart[16][16][36];
    __shared__ float rsum[16][17];

    float qreg[32];
    const float* Qp = qkv + (size_t)(q0 + qi) * 384 + h * HD;
#pragma unroll
    for (int d4 = 0; d4 < 8; ++d4) {
        float4 v = *(const float4*)(Qp + d4 * 4);
        qreg[d4 * 4 + 0] = v.x * QK_SCALE; qreg[d4 * 4 + 1] = v.y * QK_SCALE;
        qreg[d4 * 4 + 2] = v.z * QK_SCALE; qreg[d4 * 4 + 3] = v.w * QK_SCALE;
    }
    float opar[32] = {};
    float psum = 0.f;

    for (int j0 = 0; j0 < N_TOK; j0 += 64) {
        __syncthreads();
#pragma unroll
        for (int u = 0; u < 2; ++u) {
            int uu = t + u * 256;
            int r = uu >> 3, dq = (uu & 7) * 4;
            const float* src = qkv + (size_t)(j0 + r) * 384 + D_MODEL + h * HD + dq;
            float4 kv = *(const float4*)src;
            float4 vv = *(const float4*)(src + D_MODEL);
            *(float4*)&Kt[r][dq] = kv;
            *(float4*)&Vt[r][dq] = vv;
        }
        __syncthreads();
#pragma unroll
        for (int jj = 0; jj < 4; ++jj) {
            const int jl = g * 4 + jj;
            float s = 0.f;
#pragma unroll
            for (int d4 = 0; d4 < 8; ++d4) {
                float4 kv = *(const float4*)&Kt[jl][d4 * 4];
                s += qreg[d4 * 4 + 0] * kv.x + qreg[d4 * 4 + 1] * kv.y
                   + qreg[d4 * 4 + 2] * kv.z + qreg[d4 * 4 + 3] * kv.w;
            }
            float p = __expf(s);
            psum += p;
#pragma unroll
            for (int d4 = 0; d4 < 8; ++d4) {
                float4 vv = *(const float4*)&Vt[jl][d4 * 4];
                opar[d4 * 4 + 0] += p * vv.x; opar[d4 * 4 + 1] += p * vv.y;
                opar[d4 * 4 + 2] += p * vv.z; opar[d4 * 4 + 3] += p * vv.w;
            }
        }
    }

#pragma unroll
    for (int d4 = 0; d4 < 8; ++d4)
        *(float4*)&opart[g][qi][d4 * 4] = make_float4(opar[d4 * 4 + 0], opar[d4 * 4 + 1],
                                                      opar[d4 * 4 + 2], opar[d4 * 4 + 3]);
    rsum[qi][g] = psum;
    __syncthreads();

    {
        const int qi2 = t & 15;
        const int d0 = (t >> 4) * 2;
        float ssum = 0.f;
#pragma unroll
        for (int gg = 0; gg < 16; ++gg) ssum += rsum[qi2][gg];
        float inv = 1.0f / ssum;
        float o0 = 0.f, o1 = 0.f;
#pragma unroll
        for (int gg = 0; gg < 16; ++gg) {
            o0 += opart[gg][qi2][d0];
            o1 += opart[gg][qi2][d0 + 1];
        }
        unsigned short* dst = attn_ob + (size_t)(q0 + qi2) * D_MODEL + h * HD + d0;
        dst[0] = f2bf(o0 * inv);
        dst[1] = f2bf(o1 * inv);
    }
}

// ---------------- LayerNorm (+ partial reduce + bias + residual), fp32 + bf16 out ----------------
__global__ void ln_red(const float* __restrict__ in, int nz, int zstride,
                       const float* __restrict__ bias, const float* __restrict__ res,
                       const float* __restrict__ s, const float* __restrict__ b,
                       float* __restrict__ outp, unsigned short* __restrict__ outb) {
    const int i = blockIdx.x;
    const int t = threadIdx.x;  // 64
    float v0 = 0.f, v1 = 0.f;
    for (int z = 0; z < nz; ++z) {
        v0 += in[(size_t)z * zstride + i * 128 + t];
        v1 += in[(size_t)z * zstride + i * 128 + 64 + t];
    }
    if (bias) { v0 += bias[t]; v1 += bias[64 + t]; }
    if (res)  { v0 += res[i * 128 + t]; v1 += res[i * 128 + 64 + t]; }
    float sum = v0 + v1;
    for (int o = 32; o; o >>= 1) sum += __shfl_down(sum, o);
    sum = __shfl(sum, 0);
    float mean = sum * (1.0f / 128.0f);
    float d0 = v0 - mean, d1 = v1 - mean;
    float vs = d0 * d0 + d1 * d1;
    for (int o = 32; o; o >>= 1) vs += __shfl_down(vs, o);
    vs = __shfl(vs, 0);
    float inv = rsqrtf(vs * (1.0f / 128.0f) + 1e-5f);
    float r0 = d0 * inv * s[t]      + b[t];
    float r1 = d1 * inv * s[64 + t] + b[64 + t];
    outp[i * 128 + t]      = r0;
    outp[i * 128 + 64 + t] = r1;
    outb[i * 128 + t]      = f2bf(r0);
    outb[i * 128 + 64 + t] = f2bf(r1);
}

// ---------------- pair MLP (fp32 VALU) ----------------
__global__ __launch_bounds__(256) void pair_kernel(const float* __restrict__ A,
                                                   const float* __restrict__ B,
                                                   const float* __restrict__ b1,
                                                   const float* __restrict__ w2,
                                                   const float* __restrict__ b2p,
                                                   float* __restrict__ outp) {
    __shared__ float As[32][132];
    __shared__ float Bs[32][132];
    __shared__ float w2s[128];
    const int t = threadIdx.x;
    const int tx = t & 15, ty = t >> 4;
    const int i0 = blockIdx.y * 32, j0 = blockIdx.x * 32;
    for (int u = t; u < 1024; u += 256) {
        int r = u >> 5, kq = (u & 31) * 4;
        float4 av = *(const float4*)&A[(size_t)(i0 + r) * 128 + kq];
        float4 bb1 = *(const float4*)&b1[kq];
        av.x += bb1.x; av.y += bb1.y; av.z += bb1.z; av.w += bb1.w;
        *(float4*)&As[r][kq] = av;
        *(float4*)&Bs[r][kq] = *(const float4*)&B[(size_t)(j0 + r) * 128 + kq];
    }
    if (t < 32) *(float4*)&w2s[t * 4] = *(const float4*)&w2[t * 4];
    __syncthreads();
    float a00 = 0.f, a01 = 0.f, a10 = 0.f, a11 = 0.f;
#pragma unroll 4
    for (int k4 = 0; k4 < 32; ++k4) {
        float4 x0 = *(const float4*)&As[ty][k4 * 4];
        float4 x1 = *(const float4*)&As[ty + 16][k4 * 4];
        float4 y0 = *(const float4*)&Bs[tx][k4 * 4];
        float4 y1 = *(const float4*)&Bs[tx + 16][k4 * 4];
        float4 w = *(const float4*)&w2s[k4 * 4];
        a00 += fmaxf(x0.x + y0.x, 0.f) * w.x + fmaxf(x0.y + y0.y, 0.f) * w.y
             + fmaxf(x0.z + y0.z, 0.f) * w.z + fmaxf(x0.w + y0.w, 0.f) * w.w;
        a01 += fmaxf(x0.x + y1.x, 0.f) * w.x + fmaxf(x0.y + y1.y, 0.f) * w.y
             + fmaxf(x0.z + y1.z, 0.f) * w.z + fmaxf(x0.w + y1.w, 0.f) * w.w;
        a10 += fmaxf(x1.x + y0.x, 0.f) * w.x + fmaxf(x1.y + y0.y, 0.f) * w.y
             + fmaxf(x1.z + y0.z, 0.f) * w.z + fmaxf(x1.w + y0.w, 0.f) * w.w;
        a11 += fmaxf(x1.x + y1.x, 0.f) * w.x + fmaxf(x1.y + y1.y, 0.f) * w.y
             + fmaxf(x1.z + y1.z, 0.f) * w.z + fmaxf(x1.w + y1.w, 0.f) * w.w;
    }
    float bb = b2p[0];
    outp[(size_t)(i0 + ty) * N_TOK + j0 + tx]            = a00 + bb;
    outp[(size_t)(i0 + ty) * N_TOK + j0 + tx + 16]       = a01 + bb;
    outp[(size_t)(i0 + ty + 16) * N_TOK + j0 + tx]       = a10 + bb;
    outp[(size_t)(i0 + ty + 16) * N_TOK + j0 + tx + 16]  = a11 + bb;
}

extern "C" void kernel_launch(void* const* d_in, const int* in_sizes, int n_in,
                              void* d_out, int out_size, void* d_ws, size_t ws_size,
                              hipStream_t stream) {
    const int*   ids   = (const int*)d_in[0];
    const float* emb   = (const float*)d_in[1];
    const float* qkv_w = (const float*)d_in[2];
    const float* qkv_b = (const float*)d_in[3];
    const float* ow    = (const float*)d_in[4];
    const float* ob    = (const float*)d_in[5];
    const float* ln1_s = (const float*)d_in[6];
    const float* ln1_b = (const float*)d_in[7];
    const float* ln2_s = (const float*)d_in[8];
    const float* ln2_b = (const float*)d_in[9];
    const float* ff1_w = (const float*)d_in[10];
    const float* ff1_b = (const float*)d_in[11];
    const float* ff2_w = (const float*)d_in[12];
    const float* ff2_b = (const float*)d_in[13];
    const float* w1    = (const float*)d_in[14];
    const float* b1    = (const float*)d_in[15];
    const float* w2    = (const float*)d_in[16];
    const float* b2    = (const float*)d_in[17];
    float* out = (float*)d_out;

    float* ws = (float*)d_ws;
    float* x        = ws;                          // 131072
    unsigned short* xb      = (unsigned short*)(ws + 131072);     // 131072 bf16 (65536 slots)
    float* qkvb     = ws + 196608;                 // 393216
    unsigned short* attn_ob = (unsigned short*)(ws + 589824);     // 131072 bf16 (65536)
    float* tmp      = ws + 655360;                 // 131072
    unsigned short* ffb     = (unsigned short*)(ws + 786432);     // 2097152 bf16 (1048576)
    float* part     = ws + 1835008;                // 8*131072 = 1048576
    float* pab      = ws + 2883584;                // 262144 (pa | pb)
    unsigned short* qkv_wb  = (unsigned short*)(ws + 3145728);    // 98304 bf16
    unsigned short* owb     = (unsigned short*)(ws + 3194880);    // 32768 bf16
    unsigned short* ff1b    = (unsigned short*)(ws + 3211264);    // 524288 bf16
    unsigned short* ff2b    = (unsigned short*)(ws + 3473408);    // 524288 bf16
    unsigned short* w1L     = (unsigned short*)(ws + 3735552);    // 16384 bf16
    unsigned short* w1R     = (unsigned short*)(ws + 3743744);    // 16384 bf16

    // weight conversion
    cvt4_kernel<<<4608, 256, 0, stream>>>(qkv_w, 98304, ow, 32768, ff1_w, 524288,
                                          ff2_w, 524288, qkv_wb, owb, ff1b, ff2b);
    w1split_kernel<<<128, 256, 0, stream>>>(w1, w1L, w1R);

    embed_kernel<<<128, 256, 0, stream>>>(ids, emb, x, xb);

    for (int l = 0; l < 2; ++l) {
        const unsigned short* qwb = qkv_wb + l * 384 * 128;
        const float* qb  = qkv_b + l * 384;
        const unsigned short* owl = owb + l * 128 * 128;
        const float* obl = ob + l * 128;
        const unsigned short* f1w = ff1b + l * 2048 * 128;
        const float* f1b = ff1_b + l * 2048;
        const unsigned short* f2w = ff2b + l * 128 * 2048;
        const float* f2b = ff2_b + l * 128;

        // qkv = xb @ qkv_w^T + b  -> fp32
        gemm_bf<<<dim3(6, 16, 1), 256, 0, stream>>>(xb, qwb, nullptr, qb, nullptr,
                                                    qkvb, nullptr, nullptr, 1024, 384, 128, 128, 0);
        // attention -> bf16
        attn_flash<<<dim3(64, NHEAD), 256, 0, stream>>>(qkvb, attn_ob);
        // tmp = attn_ob @ ow^T + ob + x  -> fp32
        gemm_bf<<<dim3(2, 16, 1), 256, 0, stream>>>(attn_ob, owl, nullptr, obl, x,
                                                    tmp, nullptr, nullptr, 1024, 128, 128, 128, 0);
        // x, xb = LN1(tmp)
        ln_red<<<1024, 64, 0, stream>>>(tmp, 1, 0, nullptr, nullptr,
                                        ln1_s + l * 128, ln1_b + l * 128, x, xb);
        // ffb = relu(xb @ ff1^T + b) -> bf16
        gemm_bf<<<dim3(32, 16, 1), 256, 0, stream>>>(xb, f1w, nullptr, f1b, nullptr,
                                                     nullptr, ffb, nullptr, 1024, 2048, 128, 128, 1);
        // part[z] = ffb @ ff2^T (split-K, 8 chunks of 256)
        gemm_bf<<<dim3(2, 16, 8), 256, 0, stream>>>(ffb, f2w, nullptr, nullptr, nullptr,
                                                    nullptr, nullptr, part, 1024, 128, 2048, 256, 0);
        // x, xb = LN2(sum_z part + f2b + x)
        ln_red<<<1024, 64, 0, stream>>>(part, 8, 1024 * 128, f2b, x,
                                        ln2_s + l * 128, ln2_b + l * 128, x, xb);
    }

    // pair head: pa = xb @ w1L^T, pb = xb @ w1R^T (dual-weight, z selects)
    gemm_bf<<<dim3(2, 16, 2), 256, 0, stream>>>(xb, w1L, w1R, nullptr, nullptr,
                                                pab, nullptr, nullptr, 1024, 128, 128, 128, 0);
    pair_kernel<<<dim3(32, 32), 256, 0, stream>>>(pab, pab + 1024 * 128, b1, w2, b2, out);
}

// Round 7
// 276.261 us; speedup vs baseline: 2.5760x; 1.0266x over previous
//
#include <hip/hip_runtime.h>
#include <math.h>

#define QK_SCALE 0.17677669529663687f  // 1/sqrt(32)

typedef __attribute__((ext_vector_type(8))) short bf16x8;
typedef __attribute__((ext_vector_type(4))) float f32x4;

__device__ __forceinline__ unsigned short f2bf(float f) {
    unsigned u = __float_as_uint(f);
    u = u + 0x7FFFu + ((u >> 16) & 1u);   // RNE
    return (unsigned short)(u >> 16);
}

// ---------------- fused pre: weight cvt (4608 blk) + w1 split (128 blk) + embed (128 blk) ----
__global__ void pre_kernel(const int* __restrict__ ids, const float* __restrict__ emb,
                           const float* __restrict__ qkv_w, const float* __restrict__ ow,
                           const float* __restrict__ ff1_w, const float* __restrict__ ff2_w,
                           const float* __restrict__ w1,
                           unsigned short* __restrict__ qkv_wb, unsigned short* __restrict__ owb,
                           unsigned short* __restrict__ ff1b, unsigned short* __restrict__ ff2b,
                           unsigned short* __restrict__ w1L, unsigned short* __restrict__ w1R,
                           float* __restrict__ x, unsigned short* __restrict__ xb) {
    const int blk = blockIdx.x, t = threadIdx.x;
    if (blk < 4608) {
        int i = blk * 256 + t;
        if (i < 98304)       qkv_wb[i] = f2bf(qkv_w[i]);
        else if (i < 131072) owb[i - 98304] = f2bf(ow[i - 98304]);
        else if (i < 655360) ff1b[i - 131072] = f2bf(ff1_w[i - 131072]);
        else                 ff2b[i - 655360] = f2bf(ff2_w[i - 655360]);
    } else if (blk < 4736) {
        int i = (blk - 4608) * 256 + t;          // 0..32767 over w1 (128 x 256)
        int h = i >> 8, c = i & 255;
        float v = w1[i];
        if (c < 128) w1L[h * 128 + c] = f2bf(v);
        else         w1R[h * 128 + (c - 128)] = f2bf(v);
    } else {
        int u = (blk - 4736) * 256 + t;          // 1024*32 float4
        int i = u >> 5, d4 = (u & 31) * 4;
        float4 v = *(const float4*)&emb[(size_t)ids[i] * 128 + d4];
        *(float4*)&x[i * 128 + d4] = v;
        ushort4 bv;
        bv.x = f2bf(v.x); bv.y = f2bf(v.y); bv.z = f2bf(v.z); bv.w = f2bf(v.w);
        *(ushort4*)&xb[i * 128 + d4] = bv;
    }
}

// ---------------- qkv GEMM: C(1024,384) = xb @ Wb^T + bias, fp32 out ----------------
__global__ __launch_bounds__(256) void qkv_gemm(const unsigned short* __restrict__ Xb,
                                                const unsigned short* __restrict__ Wb,
                                                const float* __restrict__ bias,
                                                float* __restrict__ C) {
    const int lane = threadIdx.x & 63, w = threadIdx.x >> 6;
    const int m0 = blockIdx.y * 64 + w * 16;
    const int n0 = blockIdx.x * 64;
    const int r16 = lane & 15, kh = lane >> 4;
    f32x4 acc[4] = {{0.f,0.f,0.f,0.f},{0.f,0.f,0.f,0.f},{0.f,0.f,0.f,0.f},{0.f,0.f,0.f,0.f}};
    const unsigned short* Ap = Xb + (size_t)(m0 + r16) * 128 + kh * 8;
    const unsigned short* Bp = Wb + (size_t)(n0 + r16) * 128 + kh * 8;
#pragma unroll
    for (int k0 = 0; k0 < 128; k0 += 32) {
        bf16x8 a = *(const bf16x8*)(Ap + k0);
#pragma unroll
        for (int nt = 0; nt < 4; ++nt) {
            bf16x8 b = *(const bf16x8*)(Bp + (size_t)nt * 16 * 128 + k0);
            acc[nt] = __builtin_amdgcn_mfma_f32_16x16x32_bf16(a, b, acc[nt], 0, 0, 0);
        }
    }
#pragma unroll
    for (int nt = 0; nt < 4; ++nt) {
        int col = n0 + nt * 16 + r16;
        float bv = bias[col];
#pragma unroll
        for (int r = 0; r < 4; ++r) {
            int row = m0 + kh * 4 + r;
            C[(size_t)row * 384 + col] = acc[nt][r] + bv;
        }
    }
}

// ---------------- flash attention (verified round 6, unchanged) ----------------
__global__ __launch_bounds__(256) void attn_flash(const float* __restrict__ qkv,
                                                  unsigned short* __restrict__ attn_ob) {
    const int h = blockIdx.y;
    const int q0 = blockIdx.x * 16;
    const int t = threadIdx.x;
    const int qi = t & 15;
    const int g = t >> 4;
    __shared__ float Kt[64][36];
    __shared__ float Vt[64][36];
    __shared__ float opart[16][16][36];
    __shared__ float rsum[16][17];

    float qreg[32];
    const float* Qp = qkv + (size_t)(q0 + qi) * 384 + h * 32;
#pragma unroll
    for (int d4 = 0; d4 < 8; ++d4) {
        float4 v = *(const float4*)(Qp + d4 * 4);
        qreg[d4 * 4 + 0] = v.x * QK_SCALE; qreg[d4 * 4 + 1] = v.y * QK_SCALE;
        qreg[d4 * 4 + 2] = v.z * QK_SCALE; qreg[d4 * 4 + 3] = v.w * QK_SCALE;
    }
    float opar[32] = {};
    float psum = 0.f;

    for (int j0 = 0; j0 < 1024; j0 += 64) {
        __syncthreads();
#pragma unroll
        for (int u = 0; u < 2; ++u) {
            int uu = t + u * 256;
            int r = uu >> 3, dq = (uu & 7) * 4;
            const float* src = qkv + (size_t)(j0 + r) * 384 + 128 + h * 32 + dq;
            float4 kv = *(const float4*)src;
            float4 vv = *(const float4*)(src + 128);
            *(float4*)&Kt[r][dq] = kv;
            *(float4*)&Vt[r][dq] = vv;
        }
        __syncthreads();
#pragma unroll
        for (int jj = 0; jj < 4; ++jj) {
            const int jl = g * 4 + jj;
            float s = 0.f;
#pragma unroll
            for (int d4 = 0; d4 < 8; ++d4) {
                float4 kv = *(const float4*)&Kt[jl][d4 * 4];
                s += qreg[d4 * 4 + 0] * kv.x + qreg[d4 * 4 + 1] * kv.y
                   + qreg[d4 * 4 + 2] * kv.z + qreg[d4 * 4 + 3] * kv.w;
            }
            float p = __expf(s);
            psum += p;
#pragma unroll
            for (int d4 = 0; d4 < 8; ++d4) {
                float4 vv = *(const float4*)&Vt[jl][d4 * 4];
                opar[d4 * 4 + 0] += p * vv.x; opar[d4 * 4 + 1] += p * vv.y;
                opar[d4 * 4 + 2] += p * vv.z; opar[d4 * 4 + 3] += p * vv.w;
            }
        }
    }

#pragma unroll
    for (int d4 = 0; d4 < 8; ++d4)
        *(float4*)&opart[g][qi][d4 * 4] = make_float4(opar[d4 * 4 + 0], opar[d4 * 4 + 1],
                                                      opar[d4 * 4 + 2], opar[d4 * 4 + 3]);
    rsum[qi][g] = psum;
    __syncthreads();
    {
        const int qi2 = t & 15;
        const int d0 = (t >> 4) * 2;
        float ssum = 0.f;
#pragma unroll
        for (int gg = 0; gg < 16; ++gg) ssum += rsum[qi2][gg];
        float inv = 1.0f / ssum;
        float o0 = 0.f, o1 = 0.f;
#pragma unroll
        for (int gg = 0; gg < 16; ++gg) {
            o0 += opart[gg][qi2][d0];
            o1 += opart[gg][qi2][d0 + 1];
        }
        unsigned short* dst = attn_ob + (size_t)(q0 + qi2) * 128 + h * 32 + d0;
        dst[0] = f2bf(o0 * inv);
        dst[1] = f2bf(o1 * inv);
    }
}

// ---------------- mega MLP: proj+res+LN1 + FF1 + FF2+res+LN2 (+pa/pb on last layer) ----
// grid 64 blocks x 256 threads (4 waves). Block owns 16 token rows.
__global__ __launch_bounds__(256) void mega_mlp(
    const unsigned short* __restrict__ attn_ob, const unsigned short* __restrict__ owb,
    const float* __restrict__ ob, const float* __restrict__ x_res,
    const float* __restrict__ ln1_s, const float* __restrict__ ln1_b,
    const unsigned short* __restrict__ f1w, const float* __restrict__ f1bias,
    const unsigned short* __restrict__ f2w, const float* __restrict__ f2bias,
    const float* __restrict__ ln2_s, const float* __restrict__ ln2_b,
    float* __restrict__ x_out, unsigned short* __restrict__ xb_out,
    const unsigned short* __restrict__ w1L, const unsigned short* __restrict__ w1R,
    float* __restrict__ pab, int do_pair) {
    __shared__ unsigned short fflds[16 * 2048];   // XOR-swizzled: elem = row*2048 + (col ^ ((row&7)<<3))
    __shared__ float ylds[16][132];
    __shared__ unsigned short xlds[16 * 128];     // XOR-swizzled same scheme
    const int t = threadIdx.x, lane = t & 63, w = t >> 6;
    const int r16 = lane & 15, kh = lane >> 4;
    const int r0 = blockIdx.x * 16;

    // ---- stage A: proj 16x128 + bias + residual -> ylds ----
    {
        const int n0 = w * 32;
        f32x4 acc[2] = {{0.f,0.f,0.f,0.f},{0.f,0.f,0.f,0.f}};
        const unsigned short* Ap = attn_ob + (size_t)(r0 + r16) * 128 + kh * 8;
        const unsigned short* Bp = owb + (size_t)(n0 + r16) * 128 + kh * 8;
#pragma unroll
        for (int k0 = 0; k0 < 128; k0 += 32) {
            bf16x8 a = *(const bf16x8*)(Ap + k0);
#pragma unroll
            for (int nt = 0; nt < 2; ++nt) {
                bf16x8 b = *(const bf16x8*)(Bp + (size_t)nt * 16 * 128 + k0);
                acc[nt] = __builtin_amdgcn_mfma_f32_16x16x32_bf16(a, b, acc[nt], 0, 0, 0);
            }
        }
#pragma unroll
        for (int nt = 0; nt < 2; ++nt) {
            int col = n0 + nt * 16 + r16;
            float bv = ob[col];
#pragma unroll
            for (int r = 0; r < 4; ++r) {
                int rl = kh * 4 + r;
                ylds[rl][col] = acc[nt][r] + bv + x_res[(size_t)(r0 + rl) * 128 + col];
            }
        }
    }
    __syncthreads();

    // ---- LN1: ylds in-place + xlds (bf16, swizzled) ----
    {
        int row = t >> 4, c0 = (t & 15) * 8;
        float4 va = *(float4*)&ylds[row][c0];
        float4 vb = *(float4*)&ylds[row][c0 + 4];
        float s1 = va.x + va.y + va.z + va.w + vb.x + vb.y + vb.z + vb.w;
        float s2 = va.x*va.x + va.y*va.y + va.z*va.z + va.w*va.w
                 + vb.x*vb.x + vb.y*vb.y + vb.z*vb.z + vb.w*vb.w;
#pragma unroll
        for (int o = 1; o < 16; o <<= 1) { s1 += __shfl_xor(s1, o); s2 += __shfl_xor(s2, o); }
        float mean = s1 * (1.0f / 128.0f);
        float inv = rsqrtf(s2 * (1.0f / 128.0f) - mean * mean + 1e-5f);
        int sw = (row & 7) << 3;
        unsigned short hb[8];
        float rv[8] = {va.x, va.y, va.z, va.w, vb.x, vb.y, vb.z, vb.w};
#pragma unroll
        for (int j = 0; j < 8; ++j) {
            int c = c0 + j;
            float r = (rv[j] - mean) * inv * ln1_s[c] + ln1_b[c];
            ylds[row][c] = r;
            hb[j] = f2bf(r);
        }
        *(ushort4*)&xlds[row * 128 + (c0 ^ sw)] = make_ushort4(hb[0], hb[1], hb[2], hb[3]);
        *(ushort4*)&xlds[row * 128 + ((c0 + 4) ^ sw)] = make_ushort4(hb[4], hb[5], hb[6], hb[7]);
    }
    __syncthreads();

    // ---- stage B: FF1 16x2048 = xlds @ f1w^T, relu -> fflds (bf16, swizzled) ----
    {
        bf16x8 a[4];
        int swa = (r16 & 7) << 3;
#pragma unroll
        for (int i = 0; i < 4; ++i)
            a[i] = *(const bf16x8*)&xlds[r16 * 128 + ((i * 32 + kh * 8) ^ swa)];
#pragma unroll
        for (int chunk = 0; chunk < 2; ++chunk) {
            int cbase = w * 512 + chunk * 256;
            f32x4 acc[16];
#pragma unroll
            for (int nt = 0; nt < 16; ++nt) acc[nt] = (f32x4){0.f, 0.f, 0.f, 0.f};
#pragma unroll
            for (int nt = 0; nt < 16; ++nt) {
                const unsigned short* Bp = f1w + (size_t)(cbase + nt * 16 + r16) * 128 + kh * 8;
#pragma unroll
                for (int k0 = 0; k0 < 4; ++k0) {
                    bf16x8 b = *(const bf16x8*)(Bp + k0 * 32);
                    acc[nt] = __builtin_amdgcn_mfma_f32_16x16x32_bf16(a[k0], b, acc[nt], 0, 0, 0);
                }
            }
#pragma unroll
            for (int nt = 0; nt < 16; ++nt) {
                int col = cbase + nt * 16 + r16;
                float bv = f1bias[col];
#pragma unroll
                for (int r = 0; r < 4; ++r) {
                    int row = kh * 4 + r;
                    float v = fmaxf(acc[nt][r] + bv, 0.f);
                    fflds[row * 2048 + (col ^ ((row & 7) << 3))] = f2bf(v);
                }
            }
        }
    }
    __syncthreads();

    // ---- stage C: FF2 16x128 (K=2048) + bias + residual(ylds) -> ylds ----
    {
        const int n0 = w * 32;
        f32x4 acc[2] = {{0.f,0.f,0.f,0.f},{0.f,0.f,0.f,0.f}};
        int swa = (r16 & 7) << 3;
#pragma unroll 8
        for (int ks = 0; ks < 64; ++ks) {
            int kk = ks * 32 + kh * 8;
            bf16x8 a = *(const bf16x8*)&fflds[r16 * 2048 + (kk ^ swa)];
#pragma unroll
            for (int nt = 0; nt < 2; ++nt) {
                bf16x8 b = *(const bf16x8*)(f2w + (size_t)(n0 + nt * 16 + r16) * 2048 + kk);
                acc[nt] = __builtin_amdgcn_mfma_f32_16x16x32_bf16(a, b, acc[nt], 0, 0, 0);
            }
        }
#pragma unroll
        for (int nt = 0; nt < 2; ++nt) {
            int col = n0 + nt * 16 + r16;
            float bv = f2bias[col];
#pragma unroll
            for (int r = 0; r < 4; ++r) {
                int rl = kh * 4 + r;
                ylds[rl][col] = acc[nt][r] + bv + ylds[rl][col];
            }
        }
    }
    __syncthreads();

    // ---- LN2: ylds -> x_out/xb_out global + xlds (swizzled) ----
    {
        int row = t >> 4, c0 = (t & 15) * 8;
        float4 va = *(float4*)&ylds[row][c0];
        float4 vb = *(float4*)&ylds[row][c0 + 4];
        float s1 = va.x + va.y + va.z + va.w + vb.x + vb.y + vb.z + vb.w;
        float s2 = va.x*va.x + va.y*va.y + va.z*va.z + va.w*va.w
                 + vb.x*vb.x + vb.y*vb.y + vb.z*vb.z + vb.w*vb.w;
#pragma unroll
        for (int o = 1; o < 16; o <<= 1) { s1 += __shfl_xor(s1, o); s2 += __shfl_xor(s2, o); }
        float mean = s1 * (1.0f / 128.0f);
        float inv = rsqrtf(s2 * (1.0f / 128.0f) - mean * mean + 1e-5f);
        int sw = (row & 7) << 3;
        float rv[8] = {va.x, va.y, va.z, va.w, vb.x, vb.y, vb.z, vb.w};
        float ro[8];
        unsigned short hb[8];
#pragma unroll
        for (int j = 0; j < 8; ++j) {
            int c = c0 + j;
            ro[j] = (rv[j] - mean) * inv * ln2_s[c] + ln2_b[c];
            hb[j] = f2bf(ro[j]);
        }
        size_t gbase = (size_t)(r0 + row) * 128 + c0;
        *(float4*)&x_out[gbase]     = make_float4(ro[0], ro[1], ro[2], ro[3]);
        *(float4*)&x_out[gbase + 4] = make_float4(ro[4], ro[5], ro[6], ro[7]);
        *(ushort4*)&xb_out[gbase]     = make_ushort4(hb[0], hb[1], hb[2], hb[3]);
        *(ushort4*)&xb_out[gbase + 4] = make_ushort4(hb[4], hb[5], hb[6], hb[7]);
        *(ushort4*)&xlds[row * 128 + (c0 ^ sw)]       = make_ushort4(hb[0], hb[1], hb[2], hb[3]);
        *(ushort4*)&xlds[row * 128 + ((c0 + 4) ^ sw)] = make_ushort4(hb[4], hb[5], hb[6], hb[7]);
    }
    if (!do_pair) return;
    __syncthreads();

    // ---- stage D: pa = x @ w1L^T, pb = x @ w1R^T (16x128 each) ----
    {
        bf16x8 a[4];
        int swa = (r16 & 7) << 3;
#pragma unroll
        for (int i = 0; i < 4; ++i)
            a[i] = *(const bf16x8*)&xlds[r16 * 128 + ((i * 32 + kh * 8) ^ swa)];
        const int n0 = w * 32;
        f32x4 accA[2] = {{0.f,0.f,0.f,0.f},{0.f,0.f,0.f,0.f}};
        f32x4 accB[2] = {{0.f,0.f,0.f,0.f},{0.f,0.f,0.f,0.f}};
#pragma unroll
        for (int k0 = 0; k0 < 4; ++k0) {
#pragma unroll
            for (int nt = 0; nt < 2; ++nt) {
                const unsigned short* BA = w1L + (size_t)(n0 + nt * 16 + r16) * 128 + kh * 8 + k0 * 32;
                const unsigned short* BB = w1R + (size_t)(n0 + nt * 16 + r16) * 128 + kh * 8 + k0 * 32;
                accA[nt] = __builtin_amdgcn_mfma_f32_16x16x32_bf16(a[k0], *(const bf16x8*)BA, accA[nt], 0, 0, 0);
                accB[nt] = __builtin_amdgcn_mfma_f32_16x16x32_bf16(a[k0], *(const bf16x8*)BB, accB[nt], 0, 0, 0);
            }
        }
#pragma unroll
        for (int nt = 0; nt < 2; ++nt) {
            int col = n0 + nt * 16 + r16;
#pragma unroll
            for (int r = 0; r < 4; ++r) {
                int row = r0 + kh * 4 + r;
                pab[(size_t)row * 128 + col] = accA[nt][r];
                pab[131072 + (size_t)row * 128 + col] = accB[nt][r];
            }
        }
    }
}

// ---------------- pair MLP (fp32 VALU, unchanged) ----------------
__global__ __launch_bounds__(256) void pair_kernel(const float* __restrict__ A,
                                                   const float* __restrict__ B,
                                                   const float* __restrict__ b1,
                                                   const float* __restrict__ w2,
                                                   const float* __restrict__ b2p,
                                                   float* __restrict__ outp) {
    __shared__ float As[32][132];
    __shared__ float Bs[32][132];
    __shared__ float w2s[128];
    const int t = threadIdx.x;
    const int tx = t & 15, ty = t >> 4;
    const int i0 = blockIdx.y * 32, j0 = blockIdx.x * 32;
    for (int u = t; u < 1024; u += 256) {
        int r = u >> 5, kq = (u & 31) * 4;
        float4 av = *(const float4*)&A[(size_t)(i0 + r) * 128 + kq];
        float4 bb1 = *(const float4*)&b1[kq];
        av.x += bb1.x; av.y += bb1.y; av.z += bb1.z; av.w += bb1.w;
        *(float4*)&As[r][kq] = av;
        *(float4*)&Bs[r][kq] = *(const float4*)&B[(size_t)(j0 + r) * 128 + kq];
    }
    if (t < 32) *(float4*)&w2s[t * 4] = *(const float4*)&w2[t * 4];
    __syncthreads();
    float a00 = 0.f, a01 = 0.f, a10 = 0.f, a11 = 0.f;
#pragma unroll 4
    for (int k4 = 0; k4 < 32; ++k4) {
        float4 x0 = *(const float4*)&As[ty][k4 * 4];
        float4 x1 = *(const float4*)&As[ty + 16][k4 * 4];
        float4 y0 = *(const float4*)&Bs[tx][k4 * 4];
        float4 y1 = *(const float4*)&Bs[tx + 16][k4 * 4];
        float4 w = *(const float4*)&w2s[k4 * 4];
        a00 += fmaxf(x0.x + y0.x, 0.f) * w.x + fmaxf(x0.y + y0.y, 0.f) * w.y
             + fmaxf(x0.z + y0.z, 0.f) * w.z + fmaxf(x0.w + y0.w, 0.f) * w.w;
        a01 += fmaxf(x0.x + y1.x, 0.f) * w.x + fmaxf(x0.y + y1.y, 0.f) * w.y
             + fmaxf(x0.z + y1.z, 0.f) * w.z + fmaxf(x0.w + y1.w, 0.f) * w.w;
        a10 += fmaxf(x1.x + y0.x, 0.f) * w.x + fmaxf(x1.y + y0.y, 0.f) * w.y
             + fmaxf(x1.z + y0.z, 0.f) * w.z + fmaxf(x1.w + y0.w, 0.f) * w.w;
        a11 += fmaxf(x1.x + y1.x, 0.f) * w.x + fmaxf(x1.y + y1.y, 0.f) * w.y
             + fmaxf(x1.z + y1.z, 0.f) * w.z + fmaxf(x1.w + y1.w, 0.f) * w.w;
    }
    float bb = b2p[0];
    outp[(size_t)(i0 + ty) * 1024 + j0 + tx]            = a00 + bb;
    outp[(size_t)(i0 + ty) * 1024 + j0 + tx + 16]       = a01 + bb;
    outp[(size_t)(i0 + ty + 16) * 1024 + j0 + tx]       = a10 + bb;
    outp[(size_t)(i0 + ty + 16) * 1024 + j0 + tx + 16]  = a11 + bb;
}

extern "C" void kernel_launch(void* const* d_in, const int* in_sizes, int n_in,
                              void* d_out, int out_size, void* d_ws, size_t ws_size,
                              hipStream_t stream) {
    const int*   ids   = (const int*)d_in[0];
    const float* emb   = (const float*)d_in[1];
    const float* qkv_w = (const float*)d_in[2];
    const float* qkv_b = (const float*)d_in[3];
    const float* ow    = (const float*)d_in[4];
    const float* ob    = (const float*)d_in[5];
    const float* ln1_s = (const float*)d_in[6];
    const float* ln1_b = (const float*)d_in[7];
    const float* ln2_s = (const float*)d_in[8];
    const float* ln2_b = (const float*)d_in[9];
    const float* ff1_w = (const float*)d_in[10];
    const float* ff1_b = (const float*)d_in[11];
    const float* ff2_w = (const float*)d_in[12];
    const float* ff2_b = (const float*)d_in[13];
    const float* w1    = (const float*)d_in[14];
    const float* b1    = (const float*)d_in[15];
    const float* w2    = (const float*)d_in[16];
    const float* b2    = (const float*)d_in[17];
    float* out = (float*)d_out;

    float* ws = (float*)d_ws;
    float*          x       = ws;                                  // 131072 f
    unsigned short* xb      = (unsigned short*)(ws + 131072);      // 65536 f slots
    float*          qkvb    = ws + 196608;                         // 393216 f
    unsigned short* attn_ob = (unsigned short*)(ws + 589824);      // 65536 f slots
    float*          pab     = ws + 655360;                         // 262144 f
    unsigned short* qkv_wb  = (unsigned short*)(ws + 917504);      // 49152 f slots
    unsigned short* owb     = (unsigned short*)(ws + 966656);      // 16384 f slots
    unsigned short* ff1b    = (unsigned short*)(ws + 983040);      // 262144 f slots
    unsigned short* ff2b    = (unsigned short*)(ws + 1245184);     // 262144 f slots
    unsigned short* w1L     = (unsigned short*)(ws + 1507328);     // 8192 f slots
    unsigned short* w1R     = (unsigned short*)(ws + 1515520);     // 8192 f slots

    pre_kernel<<<4864, 256, 0, stream>>>(ids, emb, qkv_w, ow, ff1_w, ff2_w, w1,
                                         qkv_wb, owb, ff1b, ff2b, w1L, w1R, x, xb);

    for (int l = 0; l < 2; ++l) {
        qkv_gemm<<<dim3(6, 16), 256, 0, stream>>>(xb, qkv_wb + l * 384 * 128,
                                                  qkv_b + l * 384, qkvb);
        attn_flash<<<dim3(64, 4), 256, 0, stream>>>(qkvb, attn_ob);
        mega_mlp<<<64, 256, 0, stream>>>(attn_ob, owb + l * 128 * 128, ob + l * 128, x,
                                         ln1_s + l * 128, ln1_b + l * 128,
                                         ff1b + l * 2048 * 128, ff1_b + l * 2048,
                                         ff2b + l * 128 * 2048, ff2_b + l * 128,
                                         ln2_s + l * 128, ln2_b + l * 128,
                                         x, xb, w1L, w1R, pab, l == 1);
    }

    pair_kernel<<<dim3(32, 32), 256, 0, stream>>>(pab, pab + 131072, b1, w2, b2, out);
}

// Round 8
// 240.979 us; speedup vs baseline: 2.9531x; 1.1464x over previous
//
#include <hip/hip_runtime.h>
#include <math.h>

#define QK_SCALE 0.17677669529663687f  // 1/sqrt(32)

typedef __attribute__((ext_vector_type(8))) short bf16x8;
typedef __attribute__((ext_vector_type(4))) float f32x4;

__device__ __forceinline__ unsigned short f2bf(float f) {
    unsigned u = __float_as_uint(f);
    u = u + 0x7FFFu + ((u >> 16) & 1u);   // RNE
    return (unsigned short)(u >> 16);
}

// ---------------- fused pre: weight cvt + w1 split + embed ----------------
__global__ void pre_kernel(const int* __restrict__ ids, const float* __restrict__ emb,
                           const float* __restrict__ qkv_w, const float* __restrict__ ow,
                           const float* __restrict__ ff1_w, const float* __restrict__ ff2_w,
                           const float* __restrict__ w1,
                           unsigned short* __restrict__ qkv_wb, unsigned short* __restrict__ owb,
                           unsigned short* __restrict__ ff1b, unsigned short* __restrict__ ff2b,
                           unsigned short* __restrict__ w1L, unsigned short* __restrict__ w1R,
                           float* __restrict__ x, unsigned short* __restrict__ xb) {
    const int blk = blockIdx.x, t = threadIdx.x;
    if (blk < 4608) {
        int i = blk * 256 + t;
        if (i < 98304)       qkv_wb[i] = f2bf(qkv_w[i]);
        else if (i < 131072) owb[i - 98304] = f2bf(ow[i - 98304]);
        else if (i < 655360) ff1b[i - 131072] = f2bf(ff1_w[i - 131072]);
        else                 ff2b[i - 655360] = f2bf(ff2_w[i - 655360]);
    } else if (blk < 4736) {
        int i = (blk - 4608) * 256 + t;          // w1 (128 x 256)
        int h = i >> 8, c = i & 255;
        float v = w1[i];
        if (c < 128) w1L[h * 128 + c] = f2bf(v);
        else         w1R[h * 128 + (c - 128)] = f2bf(v);
    } else {
        int u = (blk - 4736) * 256 + t;          // 1024*32 float4
        int i = u >> 5, d4 = (u & 31) * 4;
        float4 v = *(const float4*)&emb[(size_t)ids[i] * 128 + d4];
        *(float4*)&x[i * 128 + d4] = v;
        ushort4 bv;
        bv.x = f2bf(v.x); bv.y = f2bf(v.y); bv.z = f2bf(v.z); bv.w = f2bf(v.w);
        *(ushort4*)&xb[i * 128 + d4] = bv;
    }
}

// ---------------- qkv GEMM -> bf16 q(scaled)/k/v buffers ----------------
__global__ __launch_bounds__(256) void qkv_gemm(const unsigned short* __restrict__ Xb,
                                                const unsigned short* __restrict__ Wb,
                                                const float* __restrict__ bias,
                                                unsigned short* __restrict__ qb,
                                                unsigned short* __restrict__ kb,
                                                unsigned short* __restrict__ vb) {
    const int lane = threadIdx.x & 63, w = threadIdx.x >> 6;
    const int m0 = blockIdx.y * 64 + w * 16;
    const int n0 = blockIdx.x * 64;
    const int r16 = lane & 15, kh = lane >> 4;
    f32x4 acc[4] = {{0.f,0.f,0.f,0.f},{0.f,0.f,0.f,0.f},{0.f,0.f,0.f,0.f},{0.f,0.f,0.f,0.f}};
    const unsigned short* Ap = Xb + (size_t)(m0 + r16) * 128 + kh * 8;
    const unsigned short* Bp = Wb + (size_t)(n0 + r16) * 128 + kh * 8;
#pragma unroll
    for (int k0 = 0; k0 < 128; k0 += 32) {
        bf16x8 a = *(const bf16x8*)(Ap + k0);
#pragma unroll
        for (int nt = 0; nt < 4; ++nt) {
            bf16x8 b = *(const bf16x8*)(Bp + (size_t)nt * 16 * 128 + k0);
            acc[nt] = __builtin_amdgcn_mfma_f32_16x16x32_bf16(a, b, acc[nt], 0, 0, 0);
        }
    }
#pragma unroll
    for (int nt = 0; nt < 4; ++nt) {
        int col = n0 + nt * 16 + r16;
        float bv = bias[col];
#pragma unroll
        for (int r = 0; r < 4; ++r) {
            int row = m0 + kh * 4 + r;
            float v = acc[nt][r] + bv;
            if (col < 128)      qb[(size_t)row * 128 + col] = f2bf(v * QK_SCALE);
            else if (col < 256) kb[(size_t)row * 128 + col - 128] = f2bf(v);
            else                vb[(size_t)row * 128 + col - 256] = f2bf(v);
        }
    }
}

// ---------------- MFMA flash attention: block = (32 queries, 1 head) ----------------
__global__ __launch_bounds__(256) void attn_mfma(const unsigned short* __restrict__ qb,
                                                 const unsigned short* __restrict__ kb,
                                                 const unsigned short* __restrict__ vb,
                                                 unsigned short* __restrict__ attn_ob) {
    const int h = blockIdx.y, q0 = blockIdx.x * 32;
    const int t = threadIdx.x, lane = t & 63, w = t >> 6;
    const int r16 = lane & 15, kh = lane >> 4;
    const int qsub = w & 1;     // 0/1: which 16 query rows this wave owns
    const int kg = w >> 1;      // 0/1: ksub-group (QK) == dsub (PV)
    __shared__ __align__(16) unsigned short Qs[32 * 40];
    __shared__ __align__(16) unsigned short Kt[128 * 40];
    __shared__ __align__(16) unsigned short Vt[32 * 136];
    __shared__ __align__(16) unsigned short Ps[32 * 136];
    __shared__ float psum[32];

    if (t < 128) {
        int r = t >> 2, c8 = (t & 3) * 8;
        *(bf16x8*)&Qs[r * 40 + c8] = *(const bf16x8*)&qb[(size_t)(q0 + r) * 128 + h * 32 + c8];
    }
    if (t < 32) psum[t] = 0.f;
    f32x4 oacc = {0.f, 0.f, 0.f, 0.f};
    __syncthreads();

    for (int kt = 0; kt < 8; ++kt) {
        const int kbase = kt * 128;
        // stage K (row-major) and V (transposed [d][key])
#pragma unroll
        for (int rep = 0; rep < 2; ++rep) {
            int id = rep * 256 + t;
            int kr = id >> 2, d0 = (id & 3) * 8;
            *(bf16x8*)&Kt[kr * 40 + d0] =
                *(const bf16x8*)&kb[(size_t)(kbase + kr) * 128 + h * 32 + d0];
            bf16x8 vv = *(const bf16x8*)&vb[(size_t)(kbase + kr) * 128 + h * 32 + d0];
#pragma unroll
            for (int j = 0; j < 8; ++j)
                Vt[(d0 + j) * 136 + kr] = (unsigned short)vv[j];
        }
        __syncthreads();

        // S = Q @ K^T (this wave: qsub x ksubs kg*4..kg*4+3), exp, psum, P->LDS
        {
            bf16x8 aq = *(const bf16x8*)&Qs[(qsub * 16 + r16) * 40 + kh * 8];
            float p[4][4];
#pragma unroll
            for (int i = 0; i < 4; ++i) {
                int ks = kg * 4 + i;
                bf16x8 bk = *(const bf16x8*)&Kt[(ks * 16 + r16) * 40 + kh * 8];
                f32x4 s = {0.f, 0.f, 0.f, 0.f};
                s = __builtin_amdgcn_mfma_f32_16x16x32_bf16(aq, bk, s, 0, 0, 0);
#pragma unroll
                for (int r = 0; r < 4; ++r) p[i][r] = __expf(s[r]);
            }
#pragma unroll
            for (int r = 0; r < 4; ++r) {
                float s = p[0][r] + p[1][r] + p[2][r] + p[3][r];
                s += __shfl_xor(s, 1); s += __shfl_xor(s, 2);
                s += __shfl_xor(s, 4); s += __shfl_xor(s, 8);
                if (r16 == 0) atomicAdd(&psum[qsub * 16 + kh * 4 + r], s);
            }
#pragma unroll
            for (int i = 0; i < 4; ++i) {
                int ks = kg * 4 + i;
#pragma unroll
                for (int r = 0; r < 4; ++r)
                    Ps[(qsub * 16 + kh * 4 + r) * 136 + ks * 16 + r16] = f2bf(p[i][r]);
            }
        }
        __syncthreads();

        // O += P @ V  (this wave: out subtile qsub x dsub=kg, K=128 over 4 segs)
#pragma unroll
        for (int seg = 0; seg < 4; ++seg) {
            bf16x8 ap = *(const bf16x8*)&Ps[(qsub * 16 + r16) * 136 + seg * 32 + kh * 8];
            bf16x8 bv = *(const bf16x8*)&Vt[(kg * 16 + r16) * 136 + seg * 32 + kh * 8];
            oacc = __builtin_amdgcn_mfma_f32_16x16x32_bf16(ap, bv, oacc, 0, 0, 0);
        }
        __syncthreads();
    }

#pragma unroll
    for (int r = 0; r < 4; ++r) {
        int row = qsub * 16 + kh * 4 + r;
        float o = oacc[r] / psum[row];
        attn_ob[(size_t)(q0 + row) * 128 + h * 32 + kg * 16 + r16] = f2bf(o);
    }
}

// ---------------- mega MLP (unchanged from round 7) ----------------
__global__ __launch_bounds__(256) void mega_mlp(
    const unsigned short* __restrict__ attn_ob, const unsigned short* __restrict__ owb,
    const float* __restrict__ ob, const float* __restrict__ x_res,
    const float* __restrict__ ln1_s, const float* __restrict__ ln1_b,
    const unsigned short* __restrict__ f1w, const float* __restrict__ f1bias,
    const unsigned short* __restrict__ f2w, const float* __restrict__ f2bias,
    const float* __restrict__ ln2_s, const float* __restrict__ ln2_b,
    float* __restrict__ x_out, unsigned short* __restrict__ xb_out,
    const unsigned short* __restrict__ w1L, const unsigned short* __restrict__ w1R,
    float* __restrict__ pab, int do_pair) {
    __shared__ unsigned short fflds[16 * 2048];
    __shared__ float ylds[16][132];
    __shared__ unsigned short xlds[16 * 128];
    const int t = threadIdx.x, lane = t & 63, w = t >> 6;
    const int r16 = lane & 15, kh = lane >> 4;
    const int r0 = blockIdx.x * 16;

    {
        const int n0 = w * 32;
        f32x4 acc[2] = {{0.f,0.f,0.f,0.f},{0.f,0.f,0.f,0.f}};
        const unsigned short* Ap = attn_ob + (size_t)(r0 + r16) * 128 + kh * 8;
        const unsigned short* Bp = owb + (size_t)(n0 + r16) * 128 + kh * 8;
#pragma unroll
        for (int k0 = 0; k0 < 128; k0 += 32) {
            bf16x8 a = *(const bf16x8*)(Ap + k0);
#pragma unroll
            for (int nt = 0; nt < 2; ++nt) {
                bf16x8 b = *(const bf16x8*)(Bp + (size_t)nt * 16 * 128 + k0);
                acc[nt] = __builtin_amdgcn_mfma_f32_16x16x32_bf16(a, b, acc[nt], 0, 0, 0);
            }
        }
#pragma unroll
        for (int nt = 0; nt < 2; ++nt) {
            int col = n0 + nt * 16 + r16;
            float bv = ob[col];
#pragma unroll
            for (int r = 0; r < 4; ++r) {
                int rl = kh * 4 + r;
                ylds[rl][col] = acc[nt][r] + bv + x_res[(size_t)(r0 + rl) * 128 + col];
            }
        }
    }
    __syncthreads();

    {
        int row = t >> 4, c0 = (t & 15) * 8;
        float4 va = *(float4*)&ylds[row][c0];
        float4 vb = *(float4*)&ylds[row][c0 + 4];
        float s1 = va.x + va.y + va.z + va.w + vb.x + vb.y + vb.z + vb.w;
        float s2 = va.x*va.x + va.y*va.y + va.z*va.z + va.w*va.w
                 + vb.x*vb.x + vb.y*vb.y + vb.z*vb.z + vb.w*vb.w;
#pragma unroll
        for (int o = 1; o < 16; o <<= 1) { s1 += __shfl_xor(s1, o); s2 += __shfl_xor(s2, o); }
        float mean = s1 * (1.0f / 128.0f);
        float inv = rsqrtf(s2 * (1.0f / 128.0f) - mean * mean + 1e-5f);
        int sw = (row & 7) << 3;
        unsigned short hb[8];
        float rv[8] = {va.x, va.y, va.z, va.w, vb.x, vb.y, vb.z, vb.w};
#pragma unroll
        for (int j = 0; j < 8; ++j) {
            int c = c0 + j;
            float r = (rv[j] - mean) * inv * ln1_s[c] + ln1_b[c];
            ylds[row][c] = r;
            hb[j] = f2bf(r);
        }
        *(ushort4*)&xlds[row * 128 + (c0 ^ sw)] = make_ushort4(hb[0], hb[1], hb[2], hb[3]);
        *(ushort4*)&xlds[row * 128 + ((c0 + 4) ^ sw)] = make_ushort4(hb[4], hb[5], hb[6], hb[7]);
    }
    __syncthreads();

    {
        bf16x8 a[4];
        int swa = (r16 & 7) << 3;
#pragma unroll
        for (int i = 0; i < 4; ++i)
            a[i] = *(const bf16x8*)&xlds[r16 * 128 + ((i * 32 + kh * 8) ^ swa)];
#pragma unroll
        for (int chunk = 0; chunk < 2; ++chunk) {
            int cbase = w * 512 + chunk * 256;
            f32x4 acc[16];
#pragma unroll
            for (int nt = 0; nt < 16; ++nt) acc[nt] = (f32x4){0.f, 0.f, 0.f, 0.f};
#pragma unroll
            for (int nt = 0; nt < 16; ++nt) {
                const unsigned short* Bp = f1w + (size_t)(cbase + nt * 16 + r16) * 128 + kh * 8;
#pragma unroll
                for (int k0 = 0; k0 < 4; ++k0) {
                    bf16x8 b = *(const bf16x8*)(Bp + k0 * 32);
                    acc[nt] = __builtin_amdgcn_mfma_f32_16x16x32_bf16(a[k0], b, acc[nt], 0, 0, 0);
                }
            }
#pragma unroll
            for (int nt = 0; nt < 16; ++nt) {
                int col = cbase + nt * 16 + r16;
                float bv = f1bias[col];
#pragma unroll
                for (int r = 0; r < 4; ++r) {
                    int row = kh * 4 + r;
                    float v = fmaxf(acc[nt][r] + bv, 0.f);
                    fflds[row * 2048 + (col ^ ((row & 7) << 3))] = f2bf(v);
                }
            }
        }
    }
    __syncthreads();

    {
        const int n0 = w * 32;
        f32x4 acc[2] = {{0.f,0.f,0.f,0.f},{0.f,0.f,0.f,0.f}};
        int swa = (r16 & 7) << 3;
#pragma unroll 8
        for (int ks = 0; ks < 64; ++ks) {
            int kk = ks * 32 + kh * 8;
            bf16x8 a = *(const bf16x8*)&fflds[r16 * 2048 + (kk ^ swa)];
#pragma unroll
            for (int nt = 0; nt < 2; ++nt) {
                bf16x8 b = *(const bf16x8*)(f2w + (size_t)(n0 + nt * 16 + r16) * 2048 + kk);
                acc[nt] = __builtin_amdgcn_mfma_f32_16x16x32_bf16(a, b, acc[nt], 0, 0, 0);
            }
        }
#pragma unroll
        for (int nt = 0; nt < 2; ++nt) {
            int col = n0 + nt * 16 + r16;
            float bv = f2bias[col];
#pragma unroll
            for (int r = 0; r < 4; ++r) {
                int rl = kh * 4 + r;
                ylds[rl][col] = acc[nt][r] + bv + ylds[rl][col];
            }
        }
    }
    __syncthreads();

    {
        int row = t >> 4, c0 = (t & 15) * 8;
        float4 va = *(float4*)&ylds[row][c0];
        float4 vb = *(float4*)&ylds[row][c0 + 4];
        float s1 = va.x + va.y + va.z + va.w + vb.x + vb.y + vb.z + vb.w;
        float s2 = va.x*va.x + va.y*va.y + va.z*va.z + va.w*va.w
                 + vb.x*vb.x + vb.y*vb.y + vb.z*vb.z + vb.w*vb.w;
#pragma unroll
        for (int o = 1; o < 16; o <<= 1) { s1 += __shfl_xor(s1, o); s2 += __shfl_xor(s2, o); }
        float mean = s1 * (1.0f / 128.0f);
        float inv = rsqrtf(s2 * (1.0f / 128.0f) - mean * mean + 1e-5f);
        int sw = (row & 7) << 3;
        float rv[8] = {va.x, va.y, va.z, va.w, vb.x, vb.y, vb.z, vb.w};
        float ro[8];
        unsigned short hb[8];
#pragma unroll
        for (int j = 0; j < 8; ++j) {
            int c = c0 + j;
            ro[j] = (rv[j] - mean) * inv * ln2_s[c] + ln2_b[c];
            hb[j] = f2bf(ro[j]);
        }
        size_t gbase = (size_t)(r0 + row) * 128 + c0;
        *(float4*)&x_out[gbase]     = make_float4(ro[0], ro[1], ro[2], ro[3]);
        *(float4*)&x_out[gbase + 4] = make_float4(ro[4], ro[5], ro[6], ro[7]);
        *(ushort4*)&xb_out[gbase]     = make_ushort4(hb[0], hb[1], hb[2], hb[3]);
        *(ushort4*)&xb_out[gbase + 4] = make_ushort4(hb[4], hb[5], hb[6], hb[7]);
        *(ushort4*)&xlds[row * 128 + (c0 ^ sw)]       = make_ushort4(hb[0], hb[1], hb[2], hb[3]);
        *(ushort4*)&xlds[row * 128 + ((c0 + 4) ^ sw)] = make_ushort4(hb[4], hb[5], hb[6], hb[7]);
    }
    if (!do_pair) return;
    __syncthreads();

    {
        bf16x8 a[4];
        int swa = (r16 & 7) << 3;
#pragma unroll
        for (int i = 0; i < 4; ++i)
            a[i] = *(const bf16x8*)&xlds[r16 * 128 + ((i * 32 + kh * 8) ^ swa)];
        const int n0 = w * 32;
        f32x4 accA[2] = {{0.f,0.f,0.f,0.f},{0.f,0.f,0.f,0.f}};
        f32x4 accB[2] = {{0.f,0.f,0.f,0.f},{0.f,0.f,0.f,0.f}};
#pragma unroll
        for (int k0 = 0; k0 < 4; ++k0) {
#pragma unroll
            for (int nt = 0; nt < 2; ++nt) {
                const unsigned short* BA = w1L + (size_t)(n0 + nt * 16 + r16) * 128 + kh * 8 + k0 * 32;
                const unsigned short* BB = w1R + (size_t)(n0 + nt * 16 + r16) * 128 + kh * 8 + k0 * 32;
                accA[nt] = __builtin_amdgcn_mfma_f32_16x16x32_bf16(a[k0], *(const bf16x8*)BA, accA[nt], 0, 0, 0);
                accB[nt] = __builtin_amdgcn_mfma_f32_16x16x32_bf16(a[k0], *(const bf16x8*)BB, accB[nt], 0, 0, 0);
            }
        }
#pragma unroll
        for (int nt = 0; nt < 2; ++nt) {
            int col = n0 + nt * 16 + r16;
#pragma unroll
            for (int r = 0; r < 4; ++r) {
                int row = r0 + kh * 4 + r;
                pab[(size_t)row * 128 + col] = accA[nt][r];
                pab[131072 + (size_t)row * 128 + col] = accB[nt][r];
            }
        }
    }
}

// ---------------- pair MLP v2: 64x64 tile, 4x4 microtile ----------------
__global__ __launch_bounds__(256) void pair_kernel(const float* __restrict__ A,
                                                   const float* __restrict__ B,
                                                   const float* __restrict__ b1,
                                                   const float* __restrict__ w2,
                                                   const float* __restrict__ b2p,
                                                   float* __restrict__ outp) {
    __shared__ float As[64][132];      // [row][k], b1 folded
    __shared__ float Bst[128][68];     // [k][row] transposed
    __shared__ float w2s[128];
    const int t = threadIdx.x;
    const int tx = t & 15, ty = t >> 4;
    const int i0 = blockIdx.y * 64, j0 = blockIdx.x * 64;
    for (int u = t; u < 2048; u += 256) {          // 64 rows x 32 float4
        int r = u >> 5, kq = (u & 31) * 4;
        float4 av = *(const float4*)&A[(size_t)(i0 + r) * 128 + kq];
        float4 bb1 = *(const float4*)&b1[kq];
        av.x += bb1.x; av.y += bb1.y; av.z += bb1.z; av.w += bb1.w;
        *(float4*)&As[r][kq] = av;
        float4 bv = *(const float4*)&B[(size_t)(j0 + r) * 128 + kq];
        Bst[kq + 0][r] = bv.x; Bst[kq + 1][r] = bv.y;
        Bst[kq + 2][r] = bv.z; Bst[kq + 3][r] = bv.w;
    }
    if (t < 32) *(float4*)&w2s[t * 4] = *(const float4*)&w2[t * 4];
    __syncthreads();

    float acc[4][4] = {};
#pragma unroll 2
    for (int k4 = 0; k4 < 32; ++k4) {
        float4 xv0 = *(const float4*)&As[ty * 4 + 0][k4 * 4];
        float4 xv1 = *(const float4*)&As[ty * 4 + 1][k4 * 4];
        float4 xv2 = *(const float4*)&As[ty * 4 + 2][k4 * 4];
        float4 xv3 = *(const float4*)&As[ty * 4 + 3][k4 * 4];
        float4 wv  = *(const float4*)&w2s[k4 * 4];
#pragma unroll
        for (int kk = 0; kk < 4; ++kk) {
            float4 yv = *(const float4*)&Bst[k4 * 4 + kk][tx * 4];
            float wk = (kk == 0) ? wv.x : (kk == 1) ? wv.y : (kk == 2) ? wv.z : wv.w;
            float xs[4] = {
                (kk == 0) ? xv0.x : (kk == 1) ? xv0.y : (kk == 2) ? xv0.z : xv0.w,
                (kk == 0) ? xv1.x : (kk == 1) ? xv1.y : (kk == 2) ? xv1.z : xv1.w,
                (kk == 0) ? xv2.x : (kk == 1) ? xv2.y : (kk == 2) ? xv2.z : xv2.w,
                (kk == 0) ? xv3.x : (kk == 1) ? xv3.y : (kk == 2) ? xv3.z : xv3.w };
#pragma unroll
            for (int i = 0; i < 4; ++i) {
                acc[i][0] += fmaxf(xs[i] + yv.x, 0.f) * wk;
                acc[i][1] += fmaxf(xs[i] + yv.y, 0.f) * wk;
                acc[i][2] += fmaxf(xs[i] + yv.z, 0.f) * wk;
                acc[i][3] += fmaxf(xs[i] + yv.w, 0.f) * wk;
            }
        }
    }
    float bb = b2p[0];
#pragma unroll
    for (int i = 0; i < 4; ++i) {
        float4 v = make_float4(acc[i][0] + bb, acc[i][1] + bb, acc[i][2] + bb, acc[i][3] + bb);
        *(float4*)&outp[(size_t)(i0 + ty * 4 + i) * 1024 + j0 + tx * 4] = v;
    }
}

extern "C" void kernel_launch(void* const* d_in, const int* in_sizes, int n_in,
                              void* d_out, int out_size, void* d_ws, size_t ws_size,
                              hipStream_t stream) {
    const int*   ids   = (const int*)d_in[0];
    const float* emb   = (const float*)d_in[1];
    const float* qkv_w = (const float*)d_in[2];
    const float* qkv_b = (const float*)d_in[3];
    const float* ow    = (const float*)d_in[4];
    const float* ob    = (const float*)d_in[5];
    const float* ln1_s = (const float*)d_in[6];
    const float* ln1_b = (const float*)d_in[7];
    const float* ln2_s = (const float*)d_in[8];
    const float* ln2_b = (const float*)d_in[9];
    const float* ff1_w = (const float*)d_in[10];
    const float* ff1_b = (const float*)d_in[11];
    const float* ff2_w = (const float*)d_in[12];
    const float* ff2_b = (const float*)d_in[13];
    const float* w1    = (const float*)d_in[14];
    const float* b1    = (const float*)d_in[15];
    const float* w2    = (const float*)d_in[16];
    const float* b2    = (const float*)d_in[17];
    float* out = (float*)d_out;

    float* ws = (float*)d_ws;
    float*          x       = ws;                                  // 131072
    unsigned short* xb      = (unsigned short*)(ws + 131072);      // 65536 f-slots
    unsigned short* qb      = (unsigned short*)(ws + 196608);      // 65536
    unsigned short* kb      = (unsigned short*)(ws + 262144);      // 65536
    unsigned short* vb      = (unsigned short*)(ws + 327680);      // 65536
    unsigned short* attn_ob = (unsigned short*)(ws + 393216);      // 65536
    float*          pab     = ws + 458752;                         // 262144
    unsigned short* qkv_wb  = (unsigned short*)(ws + 720896);      // 49152
    unsigned short* owb     = (unsigned short*)(ws + 770048);      // 16384
    unsigned short* ff1b    = (unsigned short*)(ws + 786432);      // 262144
    unsigned short* ff2b    = (unsigned short*)(ws + 1048576);     // 262144
    unsigned short* w1L     = (unsigned short*)(ws + 1310720);     // 8192
    unsigned short* w1R     = (unsigned short*)(ws + 1318912);     // 8192

    pre_kernel<<<4864, 256, 0, stream>>>(ids, emb, qkv_w, ow, ff1_w, ff2_w, w1,
                                         qkv_wb, owb, ff1b, ff2b, w1L, w1R, x, xb);

    for (int l = 0; l < 2; ++l) {
        qkv_gemm<<<dim3(6, 16), 256, 0, stream>>>(xb, qkv_wb + l * 384 * 128,
                                                  qkv_b + l * 384, qb, kb, vb);
        attn_mfma<<<dim3(32, 4), 256, 0, stream>>>(qb, kb, vb, attn_ob);
        mega_mlp<<<64, 256, 0, stream>>>(attn_ob, owb + l * 128 * 128, ob + l * 128, x,
                                         ln1_s + l * 128, ln1_b + l * 128,
                                         ff1b + l * 2048 * 128, ff1_b + l * 2048,
                                         ff2b + l * 128 * 2048, ff2_b + l * 128,
                                         ln2_s + l * 128, ln2_b + l * 128,
                                         x, xb, w1L, w1R, pab, l == 1);
    }

    pair_kernel<<<dim3(16, 16), 256, 0, stream>>>(pab, pab + 131072, b1, w2, b2, out);
}